// Round 1
// baseline (18915.361 us; speedup 1.0000x reference)
//
#include <hip/hip_runtime.h>
#include <hip/hip_bf16.h>
#include <hip/hip_cooperative_groups.h>

namespace cg = cooperative_groups;

typedef short v8s __attribute__((ext_vector_type(8)));
typedef float v4f __attribute__((ext_vector_type(4)));

__device__ __forceinline__ float bf2f(unsigned short u) {
    union { unsigned int i; float f; } v; v.i = ((unsigned int)u) << 16; return v.f;
}
__device__ __forceinline__ unsigned short f2bf(float f) {
    union { float f; unsigned int i; } v; v.f = f;
    unsigned int x = v.i;
    return (unsigned short)((x + 0x7fffu + ((x >> 16) & 1u)) >> 16);
}
__device__ __forceinline__ float sigmoidf_(float x) { return 1.0f / (1.0f + expf(-x)); }

// ---------------------------------------------------------------------------
// Tiled bf16-MFMA GEMM: C[M,N] = act(A[M,K] @ W[N,K]^T + b1[n] (+ b2[n]))
// A: float or bf16(ushort). C: float or bf16(ushort). 64x64 tile, BK=32.
// 256 threads = 4 waves; wave computes 32x32 (2x2 MFMA 16x16x32 subtiles).
// C/D layout (verified m89/m91): row = quad*4 + reg, col = lane&15.
// ---------------------------------------------------------------------------
template <typename AT, typename OT, bool TANH>
__global__ void gemm_bt(const AT* __restrict__ Ag, const float* __restrict__ Wg,
                        const float* __restrict__ b1, const float* __restrict__ b2,
                        OT* __restrict__ Cg, int M, int N, int K)
{
    __shared__ unsigned short Al[64 * 40];   // stride 40 bf16 (80B, 16B-aligned, 2-way banks = free)
    __shared__ unsigned short Bl[64 * 40];
    const int tid  = threadIdx.x;
    const int wave = tid >> 6;
    const int lane = tid & 63;
    const int quad = lane >> 4;
    const int lr   = lane & 15;
    const int m0   = blockIdx.y * 64;
    const int n0   = blockIdx.x * 64;
    const int mh   = (wave & 1) * 32;
    const int nh   = (wave >> 1) * 32;
    const int srow = tid >> 2;          // 0..63
    const int scol = (tid & 3) * 8;     // 0,8,16,24

    v4f zz = {0.f, 0.f, 0.f, 0.f};
    v4f acc[2][2] = {{zz, zz}, {zz, zz}};

    for (int k0 = 0; k0 < K; k0 += 32) {
        __syncthreads();
        // stage A tile (convert fp32 -> bf16 if needed)
        {
            const AT* src = Ag + (size_t)(m0 + srow) * K + (k0 + scol);
            if constexpr (sizeof(AT) == 4) {
                float4 f0 = *(const float4*)(src);
                float4 f1 = *(const float4*)(src + 4);
                unsigned short t8[8];
                t8[0] = f2bf(f0.x); t8[1] = f2bf(f0.y); t8[2] = f2bf(f0.z); t8[3] = f2bf(f0.w);
                t8[4] = f2bf(f1.x); t8[5] = f2bf(f1.y); t8[6] = f2bf(f1.z); t8[7] = f2bf(f1.w);
                *(v8s*)&Al[srow * 40 + scol] = *(const v8s*)t8;
            } else {
                *(v8s*)&Al[srow * 40 + scol] = *(const v8s*)src;
            }
        }
        // stage B tile (W is fp32; guard rows >= N for N=1000 case)
        {
            int nr = n0 + srow;
            unsigned short t8[8];
            if (nr < N) {
                const float* src = Wg + (size_t)nr * K + (k0 + scol);
                float4 f0 = *(const float4*)(src);
                float4 f1 = *(const float4*)(src + 4);
                t8[0] = f2bf(f0.x); t8[1] = f2bf(f0.y); t8[2] = f2bf(f0.z); t8[3] = f2bf(f0.w);
                t8[4] = f2bf(f1.x); t8[5] = f2bf(f1.y); t8[6] = f2bf(f1.z); t8[7] = f2bf(f1.w);
            } else {
                #pragma unroll
                for (int j = 0; j < 8; ++j) t8[j] = 0;
            }
            *(v8s*)&Bl[srow * 40 + scol] = *(const v8s*)t8;
        }
        __syncthreads();
        v8s a0  = *(const v8s*)&Al[(mh + lr) * 40 + quad * 8];
        v8s a1  = *(const v8s*)&Al[(mh + 16 + lr) * 40 + quad * 8];
        v8s bb0 = *(const v8s*)&Bl[(nh + lr) * 40 + quad * 8];
        v8s bb1 = *(const v8s*)&Bl[(nh + 16 + lr) * 40 + quad * 8];
        acc[0][0] = __builtin_amdgcn_mfma_f32_16x16x32_bf16(a0, bb0, acc[0][0], 0, 0, 0);
        acc[0][1] = __builtin_amdgcn_mfma_f32_16x16x32_bf16(a0, bb1, acc[0][1], 0, 0, 0);
        acc[1][0] = __builtin_amdgcn_mfma_f32_16x16x32_bf16(a1, bb0, acc[1][0], 0, 0, 0);
        acc[1][1] = __builtin_amdgcn_mfma_f32_16x16x32_bf16(a1, bb1, acc[1][1], 0, 0, 0);
    }

    #pragma unroll
    for (int i = 0; i < 2; ++i) {
        #pragma unroll
        for (int j = 0; j < 2; ++j) {
            int nn = n0 + nh + j * 16 + lr;
            if (nn < N) {
                float bias = b1[nn] + (b2 ? b2[nn] : 0.f);
                #pragma unroll
                for (int r = 0; r < 4; ++r) {
                    int mm = m0 + mh + i * 16 + quad * 4 + r;
                    float v = acc[i][j][r] + bias;
                    if (TANH) v = tanhf(v);
                    if constexpr (sizeof(OT) == 2) Cg[(size_t)mm * N + nn] = f2bf(v);
                    else                            Cg[(size_t)mm * N + nn] = v;
                }
            }
        }
    }
}

// fp32 -> bf16 bulk convert (for Whh)
__global__ void cvt_bf16(const float* __restrict__ src, unsigned short* __restrict__ dst, int n)
{
    int i = blockIdx.x * 256 + threadIdx.x;
    if (i < n) dst[i] = f2bf(src[i]);
}

// ---------------------------------------------------------------------------
// Persistent cooperative LSTM scan. 256 WGs x 256 threads (1 per CU).
// WG (b-tile 32) x (k-tile 16); wave g computes gate g's 32x16 pre-activations
// via MFMA (operands straight from L2-resident global bf16), gates exchanged
// through LDS, cell update local. One grid.sync per step; hp parity-buffered.
// done-mask for step t+1 applied at write time of step t.
// ---------------------------------------------------------------------------
__global__ __launch_bounds__(256, 1)
void lstm_scan(const unsigned short* __restrict__ XG,   // TB x 2048 bf16 (x-gates + both biases)
               const unsigned short* __restrict__ H2,   // TB x 512 bf16 (trunk out, residual)
               const unsigned short* __restrict__ Whb,  // 2048 x 512 bf16
               const float* __restrict__ h0,
               const float* __restrict__ c0,
               const int* __restrict__ done,
               unsigned short* __restrict__ hp0,
               unsigned short* __restrict__ hp1,
               float* __restrict__ cp,
               unsigned short* __restrict__ NH,          // TB x 512 bf16 (h_t + H2)
               int T)
{
    constexpr int B = 256, L = 512;
    const int wg   = blockIdx.x;
    const int b0   = (wg >> 5) * 32;
    const int k0   = (wg & 31) * 16;
    const int tid  = threadIdx.x;
    const int wave = tid >> 6;
    const int lane = tid & 63;
    const int quad = lane >> 4;
    const int lr   = lane & 15;

    __shared__ float Gl[4][32 * 16];

    // init masked state for step 0
    for (int e = tid; e < 512; e += 256) {
        int bl = e >> 4, kl = e & 15;
        int b = b0 + bl, k = k0 + kl;
        float m = 1.f - (float)done[b];
        hp0[b * L + k] = f2bf(h0[b * L + k] * m);
        cp[b * L + k]  = c0[b * L + k] * m;
    }
    __threadfence();

    cg::grid_group grid = cg::this_grid();

    const unsigned short* Wrow = Whb + (size_t)(wave * 512 + k0 + lr) * L;

    for (int t = 0; t < T; ++t) {
        grid.sync();
        const unsigned short* hpR = (t & 1) ? hp1 : hp0;
        unsigned short*       hpW = (t & 1) ? hp0 : hp1;

        v4f acc0 = {0.f, 0.f, 0.f, 0.f};
        v4f acc1 = {0.f, 0.f, 0.f, 0.f};
        const unsigned short* arow0 = hpR + (size_t)(b0 + lr) * L;
        const unsigned short* arow1 = hpR + (size_t)(b0 + 16 + lr) * L;
        #pragma unroll 4
        for (int kc = 0; kc < 16; ++kc) {
            int ko = kc * 32 + quad * 8;
            v8s bfr = *(const v8s*)(Wrow + ko);
            v8s a0  = *(const v8s*)(arow0 + ko);
            v8s a1  = *(const v8s*)(arow1 + ko);
            acc0 = __builtin_amdgcn_mfma_f32_16x16x32_bf16(a0, bfr, acc0, 0, 0, 0);
            acc1 = __builtin_amdgcn_mfma_f32_16x16x32_bf16(a1, bfr, acc1, 0, 0, 0);
        }
        // publish this wave's gate tile to LDS
        #pragma unroll
        for (int r = 0; r < 4; ++r) {
            Gl[wave][(quad * 4 + r) * 16 + lr]      = acc0[r];
            Gl[wave][(16 + quad * 4 + r) * 16 + lr] = acc1[r];
        }
        __syncthreads();
        // cell update for owned (b,k) elements
        for (int e = tid; e < 512; e += 256) {
            int bl = e >> 4, kl = e & 15;
            int b = b0 + bl, k = k0 + kl;
            size_t row   = (size_t)t * B + b;
            size_t xbase = row * 2048 + k;
            float gi = Gl[0][bl * 16 + kl] + bf2f(XG[xbase]);
            float gf = Gl[1][bl * 16 + kl] + bf2f(XG[xbase + 512]);
            float gg = Gl[2][bl * 16 + kl] + bf2f(XG[xbase + 1024]);
            float go = Gl[3][bl * 16 + kl] + bf2f(XG[xbase + 1536]);
            float iv = sigmoidf_(gi);
            float fv = sigmoidf_(gf);
            float gv = tanhf(gg);
            float ov = sigmoidf_(go);
            float c  = fv * cp[b * L + k] + iv * gv;
            float h  = ov * tanhf(c);
            NH[row * L + k] = f2bf(h + bf2f(H2[row * L + k]));
            float mn = (t + 1 < T) ? (1.f - (float)done[(t + 1) * B + b]) : 0.f;
            hpW[b * L + k] = f2bf(h * mn);
            cp[b * L + k]  = c * mn;
        }
        __threadfence();
    }
}

// ---------------------------------------------------------------------------
// Actor head reduction: one wave per row over 1000 logits.
// Online (m, Z=sum e^{x-m}, S=sum x e^{x-m}); lp = x_a - lse; ent = lse - S/Z.
// ---------------------------------------------------------------------------
__global__ void head_reduce(const float* __restrict__ logits, const int* __restrict__ action,
                            float* __restrict__ out, int TB, int A)
{
    int r = blockIdx.x * 4 + (threadIdx.x >> 6);
    int lane = threadIdx.x & 63;
    const float* row = logits + (size_t)r * A;
    float m = -1e30f, Z = 0.f, S = 0.f;
    for (int c = lane; c < A; c += 64) {
        float xv = row[c];
        if (xv > m) { float s = expf(m - xv); Z *= s; S *= s; m = xv; }
        float e = expf(xv - m);
        Z += e; S += xv * e;
    }
    #pragma unroll
    for (int off = 32; off > 0; off >>= 1) {
        float m2 = __shfl_xor(m, off);
        float Z2 = __shfl_xor(Z, off);
        float S2 = __shfl_xor(S, off);
        float M  = fmaxf(m, m2);
        float s1 = expf(m - M), s2 = expf(m2 - M);
        Z = Z * s1 + Z2 * s2;
        S = S * s1 + S2 * s2;
        m = M;
    }
    if (lane == 0) {
        float lse = m + logf(Z);
        float xa  = row[action[r]];
        out[r]      = xa - lse;        // lp
        out[TB + r] = lse - S / Z;     // entropy
    }
}

// critic v: one wave per row, dot(C1[r,:], Wc2) + bc2
__global__ void critic_v(const unsigned short* __restrict__ C1, const float* __restrict__ Wc2,
                         const float* __restrict__ bc2, float* __restrict__ out, int TB)
{
    int r = blockIdx.x * 4 + (threadIdx.x >> 6);
    int lane = threadIdx.x & 63;
    const unsigned short* row = C1 + (size_t)r * 512;
    v8s hv = *(const v8s*)&row[lane * 8];
    float4 w0 = *(const float4*)&Wc2[lane * 8];
    float4 w1 = *(const float4*)&Wc2[lane * 8 + 4];
    float s = bf2f((unsigned short)hv[0]) * w0.x + bf2f((unsigned short)hv[1]) * w0.y +
              bf2f((unsigned short)hv[2]) * w0.z + bf2f((unsigned short)hv[3]) * w0.w +
              bf2f((unsigned short)hv[4]) * w1.x + bf2f((unsigned short)hv[5]) * w1.y +
              bf2f((unsigned short)hv[6]) * w1.z + bf2f((unsigned short)hv[7]) * w1.w;
    #pragma unroll
    for (int off = 32; off > 0; off >>= 1) s += __shfl_xor(s, off);
    if (lane == 0) out[2 * TB + r] = s + bc2[0];
}

extern "C" void kernel_launch(void* const* d_in, const int* in_sizes, int n_in,
                              void* d_out, int out_size, void* d_ws, size_t ws_size,
                              hipStream_t stream)
{
    const float* x    = (const float*)d_in[0];
    const int*  done  = (const int*)d_in[1];
    const int*  action= (const int*)d_in[2];
    const float* W_t1 = (const float*)d_in[4];
    const float* b_t1 = (const float*)d_in[5];
    const float* W_t2 = (const float*)d_in[6];
    const float* b_t2 = (const float*)d_in[7];
    const float* Wih  = (const float*)d_in[8];
    const float* Whh  = (const float*)d_in[9];
    const float* bih  = (const float*)d_in[10];
    const float* bhh  = (const float*)d_in[11];
    const float* Wa1  = (const float*)d_in[12];
    const float* ba1  = (const float*)d_in[13];
    const float* Wa2  = (const float*)d_in[14];
    const float* ba2  = (const float*)d_in[15];
    const float* Wc1  = (const float*)d_in[16];
    const float* bc1  = (const float*)d_in[17];
    const float* Wc2  = (const float*)d_in[18];
    const float* bc2  = (const float*)d_in[19];
    const float* h0   = (const float*)d_in[20];
    const float* c0   = (const float*)d_in[21];
    float* out = (float*)d_out;

    const int TB = in_sizes[1];      // 65536
    const int Bc = 256;
    const int T  = TB / Bc;          // 256
    const int AN = 1000;

    const size_t MB = 1024 * 1024;
    char* ws = (char*)d_ws;
    unsigned short* H1  = (unsigned short*)(ws);                    //  64 MB
    unsigned short* H2  = (unsigned short*)(ws + 64 * MB);          //  64 MB
    unsigned short* XG  = (unsigned short*)(ws + 128 * MB);         // 256 MB (bf16 TBx2048)
    float*          logits = (float*)(ws + 128 * MB);               // reuse (250 MB)
    unsigned short* NH  = (unsigned short*)(ws + 384 * MB);         //  64 MB
    unsigned short* hp0 = (unsigned short*)(ws + 448 * MB);         // 256 KB
    unsigned short* hp1 = (unsigned short*)(ws + 448 * MB + 256 * 1024);
    float*          cp  = (float*)(ws + 449 * MB);                  // 512 KB
    unsigned short* Whb = (unsigned short*)(ws + 450 * MB);         //   2 MB
    unsigned short* A1  = H1;   // reuse (H1 dead after trunk-2)
    unsigned short* C1  = H2;   // reuse (H2 dead after LSTM)

    dim3 blk(256);
    const int MT = TB / 64;          // 1024 row-tiles

    // trunk
    gemm_bt<float,          unsigned short, true ><<<dim3(8,  MT), blk, 0, stream>>>(x,  W_t1, b_t1, nullptr, H1, TB, 512,  512);
    gemm_bt<unsigned short, unsigned short, true ><<<dim3(8,  MT), blk, 0, stream>>>(H1, W_t2, b_t2, nullptr, H2, TB, 512,  512);
    // x-side gates (hoisted out of the scan), both biases fused
    gemm_bt<unsigned short, unsigned short, false><<<dim3(32, MT), blk, 0, stream>>>(H2, Wih,  bih,  bhh,    XG, TB, 2048, 512);
    // Whh -> bf16 once per call
    cvt_bf16<<<(2048 * 512) / 256, blk, 0, stream>>>(Whh, Whb, 2048 * 512);

    // recurrent scan (cooperative, 256 WGs = 256 CUs)
    {
        const unsigned short* xg_p = XG;  const unsigned short* h2_p = H2;
        const unsigned short* wh_p = Whb; const float* h0_p = h0; const float* c0_p = c0;
        const int* dn_p = done;
        unsigned short* hp0_p = hp0; unsigned short* hp1_p = hp1;
        float* cp_p = cp; unsigned short* nh_p = NH; int T_p = T;
        void* args[] = {&xg_p, &h2_p, &wh_p, &h0_p, &c0_p, &dn_p,
                        &hp0_p, &hp1_p, &cp_p, &nh_p, &T_p};
        hipLaunchCooperativeKernel((const void*)lstm_scan, dim3(256), dim3(256), args, 0, stream);
    }

    // actor head
    gemm_bt<unsigned short, unsigned short, true ><<<dim3(8,  MT), blk, 0, stream>>>(NH, Wa1, ba1, nullptr, A1, TB, 512, 512);
    gemm_bt<unsigned short, float,          false><<<dim3(16, MT), blk, 0, stream>>>(A1, Wa2, ba2, nullptr, logits, TB, AN, 512);
    head_reduce<<<TB / 4, blk, 0, stream>>>(logits, action, out, TB, AN);

    // critic head
    gemm_bt<unsigned short, unsigned short, true ><<<dim3(8,  MT), blk, 0, stream>>>(NH, Wc1, bc1, nullptr, C1, TB, 512, 512);
    critic_v<<<TB / 4, blk, 0, stream>>>(C1, Wc2, bc2, out, TB);
}

// Round 2
// 2539.320 us; speedup vs baseline: 7.4490x; 7.4490x over previous
//
#include <hip/hip_runtime.h>
#include <hip/hip_bf16.h>

typedef short v8s __attribute__((ext_vector_type(8)));
typedef float v4f __attribute__((ext_vector_type(4)));

#define NR 48   // max segment length handled by parallel rounds; fixup covers the rest

__device__ __forceinline__ float bf2f(unsigned short u) {
    union { unsigned int i; float f; } v; v.i = ((unsigned int)u) << 16; return v.f;
}
__device__ __forceinline__ unsigned short f2bf(float f) {
    union { float f; unsigned int i; } v; v.f = f;
    unsigned int x = v.i;
    return (unsigned short)((x + 0x7fffu + ((x >> 16) & 1u)) >> 16);
}
__device__ __forceinline__ float sigmoidf_(float x) { return 1.0f / (1.0f + expf(-x)); }

// ---------------------------------------------------------------------------
// Tiled bf16-MFMA GEMM: C[M,N] = act((A (+A2))[M,K] @ W[N,K]^T + b1 (+b2))
// 64x64 tile, BK=32, 4 waves each 32x32. C/D: row=quad*4+reg, col=lane&15.
// ---------------------------------------------------------------------------
template <typename AT, typename OT, bool TANH, bool RESID>
__global__ void gemm_bt(const AT* __restrict__ Ag, const unsigned short* __restrict__ A2,
                        const float* __restrict__ Wg,
                        const float* __restrict__ b1, const float* __restrict__ b2,
                        OT* __restrict__ Cg, int M, int N, int K)
{
    __shared__ unsigned short Al[64 * 40];
    __shared__ unsigned short Bl[64 * 40];
    const int tid  = threadIdx.x;
    const int wave = tid >> 6;
    const int lane = tid & 63;
    const int quad = lane >> 4;
    const int lr   = lane & 15;
    const int m0   = blockIdx.y * 64;
    const int n0   = blockIdx.x * 64;
    const int mh   = (wave & 1) * 32;
    const int nh   = (wave >> 1) * 32;
    const int srow = tid >> 2;
    const int scol = (tid & 3) * 8;

    v4f zz = {0.f, 0.f, 0.f, 0.f};
    v4f acc[2][2] = {{zz, zz}, {zz, zz}};

    for (int k0 = 0; k0 < K; k0 += 32) {
        __syncthreads();
        {
            const AT* src = Ag + (size_t)(m0 + srow) * K + (k0 + scol);
            if constexpr (sizeof(AT) == 4) {
                float4 f0 = *(const float4*)(src);
                float4 f1 = *(const float4*)(src + 4);
                unsigned short t8[8];
                t8[0] = f2bf(f0.x); t8[1] = f2bf(f0.y); t8[2] = f2bf(f0.z); t8[3] = f2bf(f0.w);
                t8[4] = f2bf(f1.x); t8[5] = f2bf(f1.y); t8[6] = f2bf(f1.z); t8[7] = f2bf(f1.w);
                *(v8s*)&Al[srow * 40 + scol] = *(const v8s*)t8;
            } else if constexpr (RESID) {
                v8s h = *(const v8s*)(src);
                v8s r = *(const v8s*)(A2 + (size_t)(m0 + srow) * K + (k0 + scol));
                unsigned short t8[8];
                #pragma unroll
                for (int j = 0; j < 8; ++j)
                    t8[j] = f2bf(bf2f((unsigned short)h[j]) + bf2f((unsigned short)r[j]));
                *(v8s*)&Al[srow * 40 + scol] = *(const v8s*)t8;
            } else {
                *(v8s*)&Al[srow * 40 + scol] = *(const v8s*)src;
            }
        }
        {
            int nr = n0 + srow;
            unsigned short t8[8];
            if (nr < N) {
                const float* src = Wg + (size_t)nr * K + (k0 + scol);
                float4 f0 = *(const float4*)(src);
                float4 f1 = *(const float4*)(src + 4);
                t8[0] = f2bf(f0.x); t8[1] = f2bf(f0.y); t8[2] = f2bf(f0.z); t8[3] = f2bf(f0.w);
                t8[4] = f2bf(f1.x); t8[5] = f2bf(f1.y); t8[6] = f2bf(f1.z); t8[7] = f2bf(f1.w);
            } else {
                #pragma unroll
                for (int j = 0; j < 8; ++j) t8[j] = 0;
            }
            *(v8s*)&Bl[srow * 40 + scol] = *(const v8s*)t8;
        }
        __syncthreads();
        v8s a0  = *(const v8s*)&Al[(mh + lr) * 40 + quad * 8];
        v8s a1  = *(const v8s*)&Al[(mh + 16 + lr) * 40 + quad * 8];
        v8s bb0 = *(const v8s*)&Bl[(nh + lr) * 40 + quad * 8];
        v8s bb1 = *(const v8s*)&Bl[(nh + 16 + lr) * 40 + quad * 8];
        acc[0][0] = __builtin_amdgcn_mfma_f32_16x16x32_bf16(a0, bb0, acc[0][0], 0, 0, 0);
        acc[0][1] = __builtin_amdgcn_mfma_f32_16x16x32_bf16(a0, bb1, acc[0][1], 0, 0, 0);
        acc[1][0] = __builtin_amdgcn_mfma_f32_16x16x32_bf16(a1, bb0, acc[1][0], 0, 0, 0);
        acc[1][1] = __builtin_amdgcn_mfma_f32_16x16x32_bf16(a1, bb1, acc[1][1], 0, 0, 0);
    }

    #pragma unroll
    for (int i = 0; i < 2; ++i) {
        #pragma unroll
        for (int j = 0; j < 2; ++j) {
            int nn = n0 + nh + j * 16 + lr;
            if (nn < N) {
                float bias = b1[nn] + (b2 ? b2[nn] : 0.f);
                #pragma unroll
                for (int r = 0; r < 4; ++r) {
                    int mm = m0 + mh + i * 16 + quad * 4 + r;
                    float v = acc[i][j][r] + bias;
                    if (TANH) v = tanhf(v);
                    if constexpr (sizeof(OT) == 2) Cg[(size_t)mm * N + nn] = f2bf(v);
                    else                            Cg[(size_t)mm * N + nn] = v;
                }
            }
        }
    }
}

__global__ void cvt_bf16(const float* __restrict__ src, unsigned short* __restrict__ dst, int n)
{
    int i = blockIdx.x * 256 + threadIdx.x;
    if (i < n) dst[i] = f2bf(src[i]);
}

// ---------------------------------------------------------------------------
// Segment prep: single WG, thread b walks its column of done, builds per-round
// row lists deterministically (no contended atomics).
// rel-step s(t,b) = 0 if (t==0 || done[t,b]) else s(t-1,b)+1.
// Entries with s>=NR are left for the fixup kernel.
// ---------------------------------------------------------------------------
__global__ __launch_bounds__(256, 1)
void seg_prep(const int* __restrict__ done, int* __restrict__ rows,
              int* __restrict__ counts, int* __restrict__ offs,
              int* __restrict__ maxS, int T)
{
    __shared__ unsigned short cnt[256][NR];
    __shared__ unsigned short base[256][NR];
    __shared__ int tot[NR];
    __shared__ int goff[NR];
    __shared__ int mxl[256];
    const int b = threadIdx.x;
    #pragma unroll
    for (int s = 0; s < NR; ++s) cnt[b][s] = 0;
    int s = 0, mx = 0;
    for (int t = 0; t < T; ++t) {
        int d = done[t * 256 + b];
        s = (t == 0 || d) ? 0 : s + 1;
        if (s < NR) cnt[b][s]++;
        mx = mx > s ? mx : s;
    }
    mxl[b] = mx;
    __syncthreads();
    if (b < NR) {
        int tsum = 0;
        for (int bb = 0; bb < 256; ++bb) { base[bb][b] = (unsigned short)tsum; tsum += cnt[bb][b]; }
        tot[b] = tsum;
    }
    __syncthreads();
    if (b == 0) {
        int run = 0;
        for (int ss = 0; ss < NR; ++ss) { goff[ss] = run; run += tot[ss]; }
        int m = 0;
        for (int bb = 0; bb < 256; ++bb) m = m > mxl[bb] ? m : mxl[bb];
        *maxS = m;
    }
    __syncthreads();
    if (b < NR) { counts[b] = tot[b]; offs[b] = goff[b]; }
    s = 0;
    for (int t = 0; t < T; ++t) {
        int d = done[t * 256 + b];
        s = (t == 0 || d) ? 0 : s + 1;
        if (s < NR) {
            int idx = goff[s] + (int)base[b][s];
            base[b][s]++;
            rows[idx] = t * 256 + b;
        }
    }
}

// ---------------------------------------------------------------------------
// One LSTM round: gather-GEMM over the round's row list. Tile = 64 rows x
// 64 k-cols x 4 gates. 4 waves split rows (16 each) so every lane holds all
// 4 gates of its (row,k) positions -> fused cell update, gates never hit HBM.
// ---------------------------------------------------------------------------
__global__ __launch_bounds__(256, 2)
void lstm_round(const int* __restrict__ rows, const int* __restrict__ counts,
                const int* __restrict__ offs, int s,
                const unsigned short* __restrict__ XG,
                const unsigned short* __restrict__ Whb,
                const float* __restrict__ h0, const float* __restrict__ c0,
                const int* __restrict__ done,
                unsigned short* __restrict__ Hraw, unsigned short* __restrict__ Cst)
{
    const int M = counts[s];
    if (M == 0) return;
    const int off    = offs[s];
    const int mtiles = (M + 63) >> 6;
    const int ntiles = mtiles * 8;

    __shared__ unsigned short Al[64 * 40];
    __shared__ unsigned short Bl[4][64 * 40];
    __shared__ int rl[64];

    const int tid  = threadIdx.x;
    const int wave = tid >> 6;
    const int lane = tid & 63;
    const int quad = lane >> 4;
    const int lr   = lane & 15;
    const int srow = tid >> 2;
    const int scol = (tid & 3) * 8;

    for (int tile = blockIdx.x; tile < ntiles; tile += gridDim.x) {
        const int mt = tile >> 3;
        const int k0 = (tile & 7) * 64;
        __syncthreads();                       // protect rl/LDS from previous tile readers
        if (tid < 64) {
            int li = mt * 64 + tid;
            rl[tid] = (li < M) ? rows[off + li] : -1;
        }
        v4f zz = {0.f, 0.f, 0.f, 0.f};
        v4f acc[4][4] = {{zz,zz,zz,zz},{zz,zz,zz,zz},{zz,zz,zz,zz},{zz,zz,zz,zz}};

        for (int kk = 0; kk < 512; kk += 32) {
            __syncthreads();
            // stage A (gathered h_prev rows)
            {
                int gr = rl[srow];
                v8s av = {0,0,0,0,0,0,0,0};
                if (gr >= 0) {
                    if (s == 0) {
                        int t = gr >> 8, b = gr & 255;
                        if (t == 0 && !done[b]) {
                            const float* hsrc = h0 + (size_t)b * 512 + kk + scol;
                            float4 f0 = *(const float4*)(hsrc);
                            float4 f1 = *(const float4*)(hsrc + 4);
                            unsigned short t8[8];
                            t8[0]=f2bf(f0.x); t8[1]=f2bf(f0.y); t8[2]=f2bf(f0.z); t8[3]=f2bf(f0.w);
                            t8[4]=f2bf(f1.x); t8[5]=f2bf(f1.y); t8[6]=f2bf(f1.z); t8[7]=f2bf(f1.w);
                            av = *(const v8s*)t8;
                        }
                    } else {
                        av = *(const v8s*)&Hraw[(size_t)(gr - 256) * 512 + kk + scol];
                    }
                }
                *(v8s*)&Al[srow * 40 + scol] = av;
            }
            // stage 4 gate B-tiles
            #pragma unroll
            for (int g = 0; g < 4; ++g) {
                int n = g * 512 + k0 + srow;
                *(v8s*)&Bl[g][srow * 40 + scol] = *(const v8s*)&Whb[(size_t)n * 512 + kk + scol];
            }
            __syncthreads();
            v8s a = *(const v8s*)&Al[(wave * 16 + lr) * 40 + quad * 8];
            #pragma unroll
            for (int g = 0; g < 4; ++g) {
                #pragma unroll
                for (int j = 0; j < 4; ++j) {
                    v8s bb = *(const v8s*)&Bl[g][(j * 16 + lr) * 40 + quad * 8];
                    acc[g][j] = __builtin_amdgcn_mfma_f32_16x16x32_bf16(a, bb, acc[g][j], 0, 0, 0);
                }
            }
        }

        // fused cell update: lane owns rows quad*4+r (within wave's 16) x cols j*16+lr
        #pragma unroll
        for (int j = 0; j < 4; ++j) {
            const int k = k0 + j * 16 + lr;
            #pragma unroll
            for (int r = 0; r < 4; ++r) {
                const int rloc = wave * 16 + quad * 4 + r;
                const int gr = rl[rloc];
                if (gr < 0) continue;
                const size_t xb = (size_t)gr * 2048 + k;
                float gi = acc[0][j][r] + bf2f(XG[xb]);
                float gf = acc[1][j][r] + bf2f(XG[xb + 512]);
                float gg = acc[2][j][r] + bf2f(XG[xb + 1024]);
                float go = acc[3][j][r] + bf2f(XG[xb + 1536]);
                float cprev;
                if (s == 0) {
                    int t = gr >> 8, b = gr & 255;
                    cprev = (t == 0 && !done[b]) ? c0[(size_t)b * 512 + k] : 0.f;
                } else {
                    cprev = bf2f(Cst[(size_t)(gr - 256) * 512 + k]);
                }
                float c = sigmoidf_(gf) * cprev + sigmoidf_(gi) * tanhf(gg);
                float h = sigmoidf_(go) * tanhf(c);
                Cst[(size_t)gr * 512 + k]  = f2bf(c);
                Hraw[(size_t)gr * 512 + k] = f2bf(h);
            }
        }
    }
}

// ---------------------------------------------------------------------------
// Correctness backstop: sequentially process any (t,b) with rel-step >= NR.
// Exits immediately unless the data has a segment longer than NR.
// ---------------------------------------------------------------------------
__global__ __launch_bounds__(256, 1)
void lstm_fixup(const int* __restrict__ done, const int* __restrict__ maxS,
                const unsigned short* __restrict__ XG,
                const unsigned short* __restrict__ Whb,
                unsigned short* __restrict__ Hraw, unsigned short* __restrict__ Cst, int T)
{
    if (*maxS < NR) return;
    const int b = blockIdx.x;
    const int tid = threadIdx.x;
    __shared__ float hp[512];
    __shared__ float gl[2048];
    int s = 0;
    for (int t = 0; t < T; ++t) {
        int d = done[t * 256 + b];
        s = (t == 0 || d) ? 0 : s + 1;
        if (s >= NR) {
            const size_t pr = (size_t)(t - 1) * 256 + b;
            const size_t rr = (size_t)t * 256 + b;
            for (int k = tid; k < 512; k += 256) hp[k] = bf2f(Hraw[pr * 512 + k]);
            __syncthreads();
            for (int n = tid; n < 2048; n += 256) {
                const unsigned short* wr = Whb + (size_t)n * 512;
                float acc = 0.f;
                for (int k = 0; k < 512; ++k) acc += bf2f(wr[k]) * hp[k];
                gl[n] = acc;
            }
            __syncthreads();
            for (int k = tid; k < 512; k += 256) {
                float gi = gl[k]        + bf2f(XG[rr * 2048 + k]);
                float gf = gl[k + 512]  + bf2f(XG[rr * 2048 + k + 512]);
                float gg = gl[k + 1024] + bf2f(XG[rr * 2048 + k + 1024]);
                float go = gl[k + 1536] + bf2f(XG[rr * 2048 + k + 1536]);
                float cp = bf2f(Cst[pr * 512 + k]);
                float c  = sigmoidf_(gf) * cp + sigmoidf_(gi) * tanhf(gg);
                float h  = sigmoidf_(go) * tanhf(c);
                Cst[rr * 512 + k]  = f2bf(c);
                Hraw[rr * 512 + k] = f2bf(h);
            }
            __syncthreads();
        }
    }
}

// actor head reduction (one wave per row, online logsumexp)
__global__ void head_reduce(const float* __restrict__ logits, const int* __restrict__ action,
                            float* __restrict__ out, int TB, int A)
{
    int r = blockIdx.x * 4 + (threadIdx.x >> 6);
    int lane = threadIdx.x & 63;
    const float* row = logits + (size_t)r * A;
    float m = -1e30f, Z = 0.f, S = 0.f;
    for (int c = lane; c < A; c += 64) {
        float xv = row[c];
        if (xv > m) { float sc = expf(m - xv); Z *= sc; S *= sc; m = xv; }
        float e = expf(xv - m);
        Z += e; S += xv * e;
    }
    #pragma unroll
    for (int off = 32; off > 0; off >>= 1) {
        float m2 = __shfl_xor(m, off);
        float Z2 = __shfl_xor(Z, off);
        float S2 = __shfl_xor(S, off);
        float M  = fmaxf(m, m2);
        float s1 = expf(m - M), s2 = expf(m2 - M);
        Z = Z * s1 + Z2 * s2;
        S = S * s1 + S2 * s2;
        m = M;
    }
    if (lane == 0) {
        float lse = m + logf(Z);
        float xa  = row[action[r]];
        out[r]      = xa - lse;
        out[TB + r] = lse - S / Z;
    }
}

__global__ void critic_v(const unsigned short* __restrict__ C1, const float* __restrict__ Wc2,
                         const float* __restrict__ bc2, float* __restrict__ out, int TB)
{
    int r = blockIdx.x * 4 + (threadIdx.x >> 6);
    int lane = threadIdx.x & 63;
    const unsigned short* row = C1 + (size_t)r * 512;
    v8s hv = *(const v8s*)&row[lane * 8];
    float4 w0 = *(const float4*)&Wc2[lane * 8];
    float4 w1 = *(const float4*)&Wc2[lane * 8 + 4];
    float s = bf2f((unsigned short)hv[0]) * w0.x + bf2f((unsigned short)hv[1]) * w0.y +
              bf2f((unsigned short)hv[2]) * w0.z + bf2f((unsigned short)hv[3]) * w0.w +
              bf2f((unsigned short)hv[4]) * w1.x + bf2f((unsigned short)hv[5]) * w1.y +
              bf2f((unsigned short)hv[6]) * w1.z + bf2f((unsigned short)hv[7]) * w1.w;
    #pragma unroll
    for (int off = 32; off > 0; off >>= 1) s += __shfl_xor(s, off);
    if (lane == 0) out[2 * TB + r] = s + bc2[0];
}

extern "C" void kernel_launch(void* const* d_in, const int* in_sizes, int n_in,
                              void* d_out, int out_size, void* d_ws, size_t ws_size,
                              hipStream_t stream)
{
    const float* x    = (const float*)d_in[0];
    const int*  done  = (const int*)d_in[1];
    const int*  action= (const int*)d_in[2];
    const float* W_t1 = (const float*)d_in[4];
    const float* b_t1 = (const float*)d_in[5];
    const float* W_t2 = (const float*)d_in[6];
    const float* b_t2 = (const float*)d_in[7];
    const float* Wih  = (const float*)d_in[8];
    const float* Whh  = (const float*)d_in[9];
    const float* bih  = (const float*)d_in[10];
    const float* bhh  = (const float*)d_in[11];
    const float* Wa1  = (const float*)d_in[12];
    const float* ba1  = (const float*)d_in[13];
    const float* Wa2  = (const float*)d_in[14];
    const float* ba2  = (const float*)d_in[15];
    const float* Wc1  = (const float*)d_in[16];
    const float* bc1  = (const float*)d_in[17];
    const float* Wc2  = (const float*)d_in[18];
    const float* bc2  = (const float*)d_in[19];
    const float* h0   = (const float*)d_in[20];
    const float* c0   = (const float*)d_in[21];
    float* out = (float*)d_out;

    const int TB = in_sizes[1];      // 65536
    const int T  = TB / 256;         // 256
    const int AN = 1000;

    const size_t MB = 1024 * 1024;
    char* ws = (char*)d_ws;
    // layout (MB): [0,64) Cst | [64,128) H2 | [128,384) XG (H1 overlaps [128,192);
    //   logits fp32 overlaps [128,378) after rounds; C1 reuses [128,192) after
    //   head_reduce) | [384,448) Hraw | [448,450) Whb | [450,..) rows/counts/offs/maxS
    unsigned short* Cst  = (unsigned short*)(ws);
    unsigned short* H2   = (unsigned short*)(ws + 64 * MB);
    unsigned short* XG   = (unsigned short*)(ws + 128 * MB);
    unsigned short* H1   = (unsigned short*)(ws + 128 * MB);
    float*          logits = (float*)(ws + 128 * MB);
    unsigned short* Hraw = (unsigned short*)(ws + 384 * MB);
    unsigned short* Whb  = (unsigned short*)(ws + 448 * MB);
    int*            rows   = (int*)(ws + 450 * MB);
    int*            counts = (int*)(ws + 451 * MB);
    int*            offs   = counts + NR;
    int*            maxS   = offs + NR;
    unsigned short* A1   = Cst;                              // reuse after fixup
    unsigned short* C1   = (unsigned short*)(ws + 128 * MB); // reuse after head_reduce

    dim3 blk(256);
    const int MT = TB / 64;

    // trunk + hoisted x-side gates
    gemm_bt<float,          unsigned short, true,  false><<<dim3(8,  MT), blk, 0, stream>>>(x,  nullptr, W_t1, b_t1, nullptr, H1, TB, 512,  512);
    gemm_bt<unsigned short, unsigned short, true,  false><<<dim3(8,  MT), blk, 0, stream>>>(H1, nullptr, W_t2, b_t2, nullptr, H2, TB, 512,  512);
    gemm_bt<unsigned short, unsigned short, false, false><<<dim3(32, MT), blk, 0, stream>>>(H2, nullptr, Wih,  bih,  bhh,    XG, TB, 2048, 512);
    cvt_bf16<<<(2048 * 512) / 256, blk, 0, stream>>>(Whh, Whb, 2048 * 512);

    // segment-parallel LSTM: prep, NR gather-GEMM rounds, sequential backstop
    seg_prep<<<1, blk, 0, stream>>>(done, rows, counts, offs, maxS, T);
    for (int s = 0; s < NR; ++s) {
        int g = (s < 8) ? 512 : (s < 14) ? 256 : (s < 22) ? 64 : 16;
        lstm_round<<<g, blk, 0, stream>>>(rows, counts, offs, s, XG, Whb, h0, c0, done, Hraw, Cst);
    }
    lstm_fixup<<<256, blk, 0, stream>>>(done, maxS, XG, Whb, Hraw, Cst, T);

    // actor head (residual h + trunk fused into A staging)
    gemm_bt<unsigned short, unsigned short, true,  true ><<<dim3(8,  MT), blk, 0, stream>>>(Hraw, H2, Wa1, ba1, nullptr, A1, TB, 512, 512);
    gemm_bt<unsigned short, float,          false, false><<<dim3(16, MT), blk, 0, stream>>>(A1, nullptr, Wa2, ba2, nullptr, logits, TB, AN, 512);
    head_reduce<<<TB / 4, blk, 0, stream>>>(logits, action, out, TB, AN);

    // critic head
    gemm_bt<unsigned short, unsigned short, true,  true ><<<dim3(8,  MT), blk, 0, stream>>>(Hraw, H2, Wc1, bc1, nullptr, C1, TB, 512, 512);
    critic_v<<<TB / 4, blk, 0, stream>>>(C1, Wc2, bc2, out, TB);
}

// Round 3
// 2326.024 us; speedup vs baseline: 8.1321x; 1.0917x over previous
//
#include <hip/hip_runtime.h>
#include <hip/hip_bf16.h>

typedef short v8s __attribute__((ext_vector_type(8)));
typedef float v4f __attribute__((ext_vector_type(4)));

#define S0R 12   // rounds 0..11 via gather-GEMM; fixup covers s >= 12

__device__ __forceinline__ float bf2f(unsigned short u) {
    union { unsigned int i; float f; } v; v.i = ((unsigned int)u) << 16; return v.f;
}
__device__ __forceinline__ unsigned short f2bf(float f) {
    union { float f; unsigned int i; } v; v.f = f;
    unsigned int x = v.i;
    return (unsigned short)((x + 0x7fffu + ((x >> 16) & 1u)) >> 16);
}
__device__ __forceinline__ float sigmoidf_(float x) { return 1.0f / (1.0f + expf(-x)); }

// async global->LDS, 16B per lane; LDS dst is wave-uniform base + lane*16
__device__ __forceinline__ void gld_lds16(const unsigned short* g, unsigned short* l) {
    __builtin_amdgcn_global_load_lds(
        (const __attribute__((address_space(1))) unsigned int*)g,
        (__attribute__((address_space(3))) unsigned int*)l, 16, 0, 0);
}

// ---------------------------------------------------------------------------
// m97-style GEMM: C[M,Npad] = act(A[M,512] @ W[Npad,512]^T + b1 (+b2)), bf16.
// 128x128 tile, BK=32, global_load_lds staging, XOR-swizzled k-blocks.
// 4 waves, each 64x64 (4x4 subtiles of 16x16x32). K hardcoded 512.
// ---------------------------------------------------------------------------
template <bool TANH>
__global__ __launch_bounds__(256)
void gemm128(const unsigned short* __restrict__ Ag, const unsigned short* __restrict__ Wg,
             const float* __restrict__ b1, const float* __restrict__ b2,
             unsigned short* __restrict__ Cg, int Nreal, int Npad)
{
    __shared__ __align__(16) unsigned short As[128 * 32];
    __shared__ __align__(16) unsigned short Bs[128 * 32];
    const int tid  = threadIdx.x;
    const int w    = tid >> 6;
    const int lane = tid & 63;
    const int quad = lane >> 4;
    const int lr   = lane & 15;
    const int wm   = w & 1, wn = w >> 1;
    const int m0   = blockIdx.y * 128;
    const int n0   = blockIdx.x * 128;

    const int srow = lane >> 2;                         // 0..15 in 16-row group
    const int kblk = (lane & 3) ^ ((lane >> 3) & 3);    // swizzled 8-elem block

    const unsigned short* gA0 = Ag + (size_t)(m0 + w * 16 + srow) * 512 + kblk * 8;
    const unsigned short* gA1 = gA0 + (size_t)64 * 512;
    const unsigned short* gB0 = Wg + (size_t)(n0 + w * 16 + srow) * 512 + kblk * 8;
    const unsigned short* gB1 = gB0 + (size_t)64 * 512;
    unsigned short* lA0 = As + (w * 16) * 32;
    unsigned short* lA1 = As + (64 + w * 16) * 32;
    unsigned short* lB0 = Bs + (w * 16) * 32;
    unsigned short* lB1 = Bs + (64 + w * 16) * 32;

    const int swz = (quad ^ ((lr >> 1) & 3)) * 8;
    int aoff[4], boff[4];
    #pragma unroll
    for (int i = 0; i < 4; ++i) {
        aoff[i] = (wm * 64 + i * 16 + lr) * 32 + swz;
        boff[i] = (wn * 64 + i * 16 + lr) * 32 + swz;
    }

    v4f zz = {0.f, 0.f, 0.f, 0.f};
    v4f acc[4][4] = {{zz,zz,zz,zz},{zz,zz,zz,zz},{zz,zz,zz,zz},{zz,zz,zz,zz}};

    for (int k = 0; k < 16; ++k) {
        __syncthreads();
        gld_lds16(gA0 + k * 32, lA0);
        gld_lds16(gA1 + k * 32, lA1);
        gld_lds16(gB0 + k * 32, lB0);
        gld_lds16(gB1 + k * 32, lB1);
        __syncthreads();
        v8s a[4], b[4];
        #pragma unroll
        for (int i = 0; i < 4; ++i) { a[i] = *(const v8s*)&As[aoff[i]]; b[i] = *(const v8s*)&Bs[boff[i]]; }
        #pragma unroll
        for (int i = 0; i < 4; ++i)
            #pragma unroll
            for (int j = 0; j < 4; ++j)
                acc[i][j] = __builtin_amdgcn_mfma_f32_16x16x32_bf16(a[i], b[j], acc[i][j], 0, 0, 0);
    }

    #pragma unroll
    for (int j = 0; j < 4; ++j) {
        const int nn = n0 + wn * 64 + j * 16 + lr;
        const float bias = (nn < Nreal) ? (b1[nn] + (b2 ? b2[nn] : 0.f)) : 0.f;
        #pragma unroll
        for (int i = 0; i < 4; ++i) {
            #pragma unroll
            for (int r = 0; r < 4; ++r) {
                const int mm = m0 + wm * 64 + i * 16 + quad * 4 + r;
                float v = acc[i][j][r] + bias;
                if (TANH) v = tanhf(v);
                Cg[(size_t)mm * Npad + nn] = f2bf(v);
            }
        }
    }
}

// fp32 -> bf16, 8 elems/thread (n must be multiple of 2048)
__global__ void cvt8(const float* __restrict__ src, unsigned short* __restrict__ dst)
{
    const size_t i = ((size_t)blockIdx.x * 256 + threadIdx.x) * 8;
    float4 f0 = *(const float4*)(src + i);
    float4 f1 = *(const float4*)(src + i + 4);
    unsigned short t8[8];
    t8[0]=f2bf(f0.x); t8[1]=f2bf(f0.y); t8[2]=f2bf(f0.z); t8[3]=f2bf(f0.w);
    t8[4]=f2bf(f1.x); t8[5]=f2bf(f1.y); t8[6]=f2bf(f1.z); t8[7]=f2bf(f1.w);
    *(v8s*)(dst + i) = *(const v8s*)t8;
}

// Wa2 (1000x512 fp32) -> zero-padded 1024x512 bf16
__global__ void wa2pad(const float* __restrict__ src, unsigned short* __restrict__ dst)
{
    const int i = blockIdx.x * 256 + threadIdx.x;   // over 1024*512
    const int row = i >> 9;
    dst[i] = (row < 1000) ? f2bf(src[(size_t)row * 512 + (i & 511)]) : (unsigned short)0;
}

// masked initial state (bf16) + zero row buffer
__global__ void init_state(const float* __restrict__ h0, const float* __restrict__ c0,
                           const int* __restrict__ done,
                           unsigned short* __restrict__ h_init, unsigned short* __restrict__ c_init,
                           unsigned short* __restrict__ zbuf)
{
    const int b = blockIdx.x;
    const float m = 1.f - (float)done[b];
    for (int k = threadIdx.x; k < 512; k += 256) {
        h_init[(size_t)b * 512 + k] = f2bf(h0[(size_t)b * 512 + k] * m);
        c_init[(size_t)b * 512 + k] = f2bf(c0[(size_t)b * 512 + k] * m);
        if (b == 0) zbuf[k] = 0;
    }
}

// ---------------------------------------------------------------------------
// Segment prep: rel-step s(t,b)=0 if (t==0||done) else s+1; per-round row
// lists (concatenated, offsets) for s < S0R. Single WG, deterministic.
// ---------------------------------------------------------------------------
__global__ __launch_bounds__(256, 1)
void seg_prep(const int* __restrict__ done, int* __restrict__ rows,
              int* __restrict__ counts, int* __restrict__ offs,
              int* __restrict__ maxS, int T)
{
    __shared__ unsigned short cnt[256][S0R];
    __shared__ unsigned short base[256][S0R];
    __shared__ int tot[S0R];
    __shared__ int goff[S0R];
    __shared__ int mxl[256];
    const int b = threadIdx.x;
    #pragma unroll
    for (int s = 0; s < S0R; ++s) cnt[b][s] = 0;
    int s = 0, mx = 0;
    for (int t = 0; t < T; ++t) {
        int d = done[t * 256 + b];
        s = (t == 0 || d) ? 0 : s + 1;
        if (s < S0R) cnt[b][s]++;
        mx = mx > s ? mx : s;
    }
    mxl[b] = mx;
    __syncthreads();
    if (b < S0R) {
        int tsum = 0;
        for (int bb = 0; bb < 256; ++bb) { base[bb][b] = (unsigned short)tsum; tsum += cnt[bb][b]; }
        tot[b] = tsum;
    }
    __syncthreads();
    if (b == 0) {
        int run = 0;
        for (int ss = 0; ss < S0R; ++ss) { goff[ss] = run; run += tot[ss]; }
        int m = 0;
        for (int bb = 0; bb < 256; ++bb) m = m > mxl[bb] ? m : mxl[bb];
        *maxS = m;
    }
    __syncthreads();
    if (b < S0R) { counts[b] = tot[b]; offs[b] = goff[b]; }
    s = 0;
    for (int t = 0; t < T; ++t) {
        int d = done[t * 256 + b];
        s = (t == 0 || d) ? 0 : s + 1;
        if (s < S0R) {
            int idx = goff[s] + (int)base[b][s];
            base[b][s]++;
            rows[idx] = t * 256 + b;
        }
    }
}

// ---------------------------------------------------------------------------
// Fused LSTM round: 128 gathered rows x (4 gates x 32 hidden cols) per block,
// async-staged A (per-lane gather addresses) and Whh-B, LDS gate exchange,
// cell update in epilogue. Gates never touch HBM.
// ---------------------------------------------------------------------------
__global__ __launch_bounds__(256)
void lstm_round(const int* __restrict__ rows, const int* __restrict__ counts,
                const int* __restrict__ offs, int s,
                const unsigned short* __restrict__ XG,
                const unsigned short* __restrict__ Whb,
                const unsigned short* __restrict__ h_init,
                const unsigned short* __restrict__ c_init,
                const unsigned short* __restrict__ zbuf,
                unsigned short* __restrict__ Hraw, unsigned short* __restrict__ Cst)
{
    const int M = counts[s];
    if (M == 0) return;
    const int off    = offs[s];
    const int mtiles = (M + 127) >> 7;

    __shared__ __align__(16) unsigned short As[128 * 32];
    __shared__ __align__(16) unsigned short Bs[128 * 32];
    __shared__ __align__(16) unsigned short Gx[128 * 136];   // [row][4*32 +8 pad] bf16
    __shared__ int rl[128];

    const int tid  = threadIdx.x;
    const int w    = tid >> 6;
    const int lane = tid & 63;
    const int quad = lane >> 4;
    const int lr   = lane & 15;
    const int wm   = w & 1, wn = w >> 1;
    const int c0   = blockIdx.x * 32;                    // hidden-col tile
    const int srow = lane >> 2;
    const int kblk = (lane & 3) ^ ((lane >> 3) & 3);

    // B rows: n_local = g*32 + c  ->  W row g*512 + c0 + c
    const int br0 = w * 16 + srow;        // 0..63  (gates 0,1)
    const int br1 = 64 + br0;             // 64..127 (gates 2,3)
    const unsigned short* gB0 = Whb + (size_t)((br0 >> 5) * 512 + c0 + (br0 & 31)) * 512 + kblk * 8;
    const unsigned short* gB1 = Whb + (size_t)((br1 >> 5) * 512 + c0 + (br1 & 31)) * 512 + kblk * 8;
    unsigned short* lA0 = As + (w * 16) * 32;
    unsigned short* lA1 = As + (64 + w * 16) * 32;
    unsigned short* lB0 = Bs + (w * 16) * 32;
    unsigned short* lB1 = Bs + (64 + w * 16) * 32;

    const int swz = (quad ^ ((lr >> 1) & 3)) * 8;
    int aoff[4], boff[4];
    #pragma unroll
    for (int i = 0; i < 4; ++i) {
        aoff[i] = (wm * 64 + i * 16 + lr) * 32 + swz;
        boff[i] = (wn * 64 + i * 16 + lr) * 32 + swz;
    }

    for (int mt = blockIdx.y; mt < mtiles; mt += gridDim.y) {
        __syncthreads();                 // prior tile's LDS readers done
        if (tid < 128) {
            int li = mt * 128 + tid;
            rl[tid] = (li < M) ? rows[off + li] : -1;
        }
        __syncthreads();

        // gathered A addresses (branch-free async staging via zbuf fallback)
        int g0r = rl[w * 16 + srow];
        int g1r = rl[64 + w * 16 + srow];
        const unsigned short* gA0;
        const unsigned short* gA1;
        if (s == 0) {
            gA0 = (g0r >= 0 && g0r < 256) ? h_init + (size_t)g0r * 512 + kblk * 8 : zbuf + kblk * 8;
            gA1 = (g1r >= 0 && g1r < 256) ? h_init + (size_t)g1r * 512 + kblk * 8 : zbuf + kblk * 8;
        } else {
            gA0 = (g0r >= 0) ? Hraw + (size_t)(g0r - 256) * 512 + kblk * 8 : zbuf + kblk * 8;
            gA1 = (g1r >= 0) ? Hraw + (size_t)(g1r - 256) * 512 + kblk * 8 : zbuf + kblk * 8;
        }

        v4f zz = {0.f, 0.f, 0.f, 0.f};
        v4f acc[4][4] = {{zz,zz,zz,zz},{zz,zz,zz,zz},{zz,zz,zz,zz},{zz,zz,zz,zz}};

        for (int k = 0; k < 16; ++k) {
            __syncthreads();
            gld_lds16(gA0 + k * 32, lA0);
            gld_lds16(gA1 + k * 32, lA1);
            gld_lds16(gB0 + k * 32, lB0);
            gld_lds16(gB1 + k * 32, lB1);
            __syncthreads();
            v8s a[4], b[4];
            #pragma unroll
            for (int i = 0; i < 4; ++i) { a[i] = *(const v8s*)&As[aoff[i]]; b[i] = *(const v8s*)&Bs[boff[i]]; }
            #pragma unroll
            for (int i = 0; i < 4; ++i)
                #pragma unroll
                for (int j = 0; j < 4; ++j)
                    acc[i][j] = __builtin_amdgcn_mfma_f32_16x16x32_bf16(a[i], b[j], acc[i][j], 0, 0, 0);
        }

        // publish gate pre-activations to LDS (bf16)
        #pragma unroll
        for (int j = 0; j < 4; ++j) {
            const int nl = wn * 64 + j * 16 + lr;
            #pragma unroll
            for (int i = 0; i < 4; ++i)
                #pragma unroll
                for (int r = 0; r < 4; ++r)
                    Gx[(wm * 64 + i * 16 + quad * 4 + r) * 136 + nl] = f2bf(acc[i][j][r]);
        }
        __syncthreads();

        // fused cell update: thread owns row tid>>1, 16 hidden cols
        {
            const int rloc = tid >> 1;
            const int half = tid & 1;
            const int gr   = rl[rloc];
            if (gr >= 0) {
                #pragma unroll
                for (int ch = 0; ch < 2; ++ch) {
                    const int co = half * 16 + ch * 8;
                    const int kg = c0 + co;
                    v8s q0 = *(const v8s*)&Gx[rloc * 136 +   0 + co];
                    v8s q1 = *(const v8s*)&Gx[rloc * 136 +  32 + co];
                    v8s q2 = *(const v8s*)&Gx[rloc * 136 +  64 + co];
                    v8s q3 = *(const v8s*)&Gx[rloc * 136 +  96 + co];
                    const size_t xb = (size_t)gr * 2048 + kg;
                    v8s x0 = *(const v8s*)&XG[xb];
                    v8s x1 = *(const v8s*)&XG[xb + 512];
                    v8s x2 = *(const v8s*)&XG[xb + 1024];
                    v8s x3 = *(const v8s*)&XG[xb + 1536];
                    float cprev[8];
                    if (s == 0) {
                        if (gr < 256) {
                            v8s cv = *(const v8s*)&c_init[(size_t)gr * 512 + kg];
                            #pragma unroll
                            for (int e = 0; e < 8; ++e) cprev[e] = bf2f((unsigned short)cv[e]);
                        } else {
                            #pragma unroll
                            for (int e = 0; e < 8; ++e) cprev[e] = 0.f;
                        }
                    } else {
                        v8s cv = *(const v8s*)&Cst[(size_t)(gr - 256) * 512 + kg];
                        #pragma unroll
                        for (int e = 0; e < 8; ++e) cprev[e] = bf2f((unsigned short)cv[e]);
                    }
                    unsigned short hc[8], cc[8];
                    #pragma unroll
                    for (int e = 0; e < 8; ++e) {
                        float gi = bf2f((unsigned short)q0[e]) + bf2f((unsigned short)x0[e]);
                        float gf = bf2f((unsigned short)q1[e]) + bf2f((unsigned short)x1[e]);
                        float gg = bf2f((unsigned short)q2[e]) + bf2f((unsigned short)x2[e]);
                        float go = bf2f((unsigned short)q3[e]) + bf2f((unsigned short)x3[e]);
                        float c  = sigmoidf_(gf) * cprev[e] + sigmoidf_(gi) * tanhf(gg);
                        float h  = sigmoidf_(go) * tanhf(c);
                        cc[e] = f2bf(c);
                        hc[e] = f2bf(h);
                    }
                    *(v8s*)&Cst[(size_t)gr * 512 + kg]  = *(const v8s*)cc;
                    *(v8s*)&Hraw[(size_t)gr * 512 + kg] = *(const v8s*)hc;
                }
            }
        }
    }
}

// backstop: sequentially process (t,b) with rel-step >= S0R
__global__ __launch_bounds__(256, 1)
void lstm_fixup(const int* __restrict__ done, const int* __restrict__ maxS,
                const unsigned short* __restrict__ XG,
                const unsigned short* __restrict__ Whb,
                unsigned short* __restrict__ Hraw, unsigned short* __restrict__ Cst, int T)
{
    if (*maxS < S0R) return;
    const int b = blockIdx.x;
    const int tid = threadIdx.x;
    __shared__ __align__(16) unsigned short hp[512];
    __shared__ float gl[2048];
    int s = 0;
    for (int t = 0; t < T; ++t) {
        int d = done[t * 256 + b];
        s = (t == 0 || d) ? 0 : s + 1;
        if (s >= S0R) {
            const size_t pr = (size_t)(t - 1) * 256 + b;
            const size_t rr = (size_t)t * 256 + b;
            for (int k = tid; k < 512; k += 256) hp[k] = Hraw[pr * 512 + k];
            __syncthreads();
            for (int n = tid; n < 2048; n += 256) {
                const unsigned short* wr = Whb + (size_t)n * 512;
                float acc = 0.f;
                for (int kk = 0; kk < 512; kk += 8) {
                    v8s wv = *(const v8s*)&wr[kk];
                    v8s hv = *(const v8s*)&hp[kk];
                    #pragma unroll
                    for (int e = 0; e < 8; ++e)
                        acc += bf2f((unsigned short)wv[e]) * bf2f((unsigned short)hv[e]);
                }
                gl[n] = acc;
            }
            __syncthreads();
            for (int k = tid; k < 512; k += 256) {
                float gi = gl[k]        + bf2f(XG[rr * 2048 + k]);
                float gf = gl[k + 512]  + bf2f(XG[rr * 2048 + k + 512]);
                float gg = gl[k + 1024] + bf2f(XG[rr * 2048 + k + 1024]);
                float go = gl[k + 1536] + bf2f(XG[rr * 2048 + k + 1536]);
                float cp = bf2f(Cst[pr * 512 + k]);
                float c  = sigmoidf_(gf) * cp + sigmoidf_(gi) * tanhf(gg);
                float h  = sigmoidf_(go) * tanhf(c);
                Cst[rr * 512 + k]  = f2bf(c);
                Hraw[rr * 512 + k] = f2bf(h);
            }
            __syncthreads();
        }
    }
}

// Hraw += H2 in place (-> NH), 8 elems/thread
__global__ void nh_add(unsigned short* __restrict__ H, const unsigned short* __restrict__ H2)
{
    const size_t i = ((size_t)blockIdx.x * 256 + threadIdx.x) * 8;
    v8s a = *(const v8s*)(H + i);
    v8s b = *(const v8s*)(H2 + i);
    unsigned short t8[8];
    #pragma unroll
    for (int e = 0; e < 8; ++e)
        t8[e] = f2bf(bf2f((unsigned short)a[e]) + bf2f((unsigned short)b[e]));
    *(v8s*)(H + i) = *(const v8s*)t8;
}

// actor head: one wave per row over bf16 logits (stride 1024, 1000 valid)
__global__ void head_reduce(const unsigned short* __restrict__ logits,
                            const int* __restrict__ action,
                            float* __restrict__ out, int TB)
{
    const int r = blockIdx.x * 4 + (threadIdx.x >> 6);
    const int lane = threadIdx.x & 63;
    const unsigned short* row = logits + (size_t)r * 1024;
    float m = -1e30f, Z = 0.f, S = 0.f;
    v8s v0 = *(const v8s*)&row[lane * 8];
    #pragma unroll
    for (int e = 0; e < 8; ++e) {
        float xv = bf2f((unsigned short)v0[e]);
        if (xv > m) { float sc = expf(m - xv); Z *= sc; S *= sc; m = xv; }
        float ev = expf(xv - m);
        Z += ev; S += xv * ev;
    }
    v8s v1 = *(const v8s*)&row[512 + lane * 8];
    #pragma unroll
    for (int e = 0; e < 8; ++e) {
        int c = 512 + lane * 8 + e;
        if (c < 1000) {
            float xv = bf2f((unsigned short)v1[e]);
            if (xv > m) { float sc = expf(m - xv); Z *= sc; S *= sc; m = xv; }
            float ev = expf(xv - m);
            Z += ev; S += xv * ev;
        }
    }
    #pragma unroll
    for (int offb = 32; offb > 0; offb >>= 1) {
        float m2 = __shfl_xor(m, offb);
        float Z2 = __shfl_xor(Z, offb);
        float S2 = __shfl_xor(S, offb);
        float M  = fmaxf(m, m2);
        float s1 = expf(m - M), s2 = expf(m2 - M);
        Z = Z * s1 + Z2 * s2;
        S = S * s1 + S2 * s2;
        m = M;
    }
    if (lane == 0) {
        float lse = m + logf(Z);
        float xa  = bf2f(row[action[r]]);
        out[r]      = xa - lse;
        out[TB + r] = lse - S / Z;
    }
}

__global__ void critic_v(const unsigned short* __restrict__ C1, const float* __restrict__ Wc2,
                         const float* __restrict__ bc2, float* __restrict__ out, int TB)
{
    const int r = blockIdx.x * 4 + (threadIdx.x >> 6);
    const int lane = threadIdx.x & 63;
    const unsigned short* row = C1 + (size_t)r * 512;
    v8s hv = *(const v8s*)&row[lane * 8];
    float4 w0 = *(const float4*)&Wc2[lane * 8];
    float4 w1 = *(const float4*)&Wc2[lane * 8 + 4];
    float s = bf2f((unsigned short)hv[0]) * w0.x + bf2f((unsigned short)hv[1]) * w0.y +
              bf2f((unsigned short)hv[2]) * w0.z + bf2f((unsigned short)hv[3]) * w0.w +
              bf2f((unsigned short)hv[4]) * w1.x + bf2f((unsigned short)hv[5]) * w1.y +
              bf2f((unsigned short)hv[6]) * w1.z + bf2f((unsigned short)hv[7]) * w1.w;
    #pragma unroll
    for (int offb = 32; offb > 0; offb >>= 1) s += __shfl_xor(s, offb);
    if (lane == 0) out[2 * TB + r] = s + bc2[0];
}

extern "C" void kernel_launch(void* const* d_in, const int* in_sizes, int n_in,
                              void* d_out, int out_size, void* d_ws, size_t ws_size,
                              hipStream_t stream)
{
    const float* x    = (const float*)d_in[0];
    const int*  done  = (const int*)d_in[1];
    const int*  action= (const int*)d_in[2];
    const float* W_t1 = (const float*)d_in[4];
    const float* b_t1 = (const float*)d_in[5];
    const float* W_t2 = (const float*)d_in[6];
    const float* b_t2 = (const float*)d_in[7];
    const float* Wih  = (const float*)d_in[8];
    const float* Whh  = (const float*)d_in[9];
    const float* bih  = (const float*)d_in[10];
    const float* bhh  = (const float*)d_in[11];
    const float* Wa1  = (const float*)d_in[12];
    const float* ba1  = (const float*)d_in[13];
    const float* Wa2  = (const float*)d_in[14];
    const float* ba2  = (const float*)d_in[15];
    const float* Wc1  = (const float*)d_in[16];
    const float* bc1  = (const float*)d_in[17];
    const float* Wc2  = (const float*)d_in[18];
    const float* bc2  = (const float*)d_in[19];
    const float* h0   = (const float*)d_in[20];
    const float* c0   = (const float*)d_in[21];
    float* out = (float*)d_out;

    const int TB = in_sizes[1];      // 65536
    const int T  = TB / 256;         // 256

    const size_t MiB = 1024 * 1024;
    char* ws = (char*)d_ws;
    // [0,256) XG  (aliases: H1@0 trunk-phase; logits@0..128 + A1/C1@136..200 head-phase)
    // [256,320) Cst | [320,384) H2 | [384,448) Hraw (alias xbf pre-rounds) | [448,~456) weights/meta
    unsigned short* XG     = (unsigned short*)(ws);
    unsigned short* H1     = (unsigned short*)(ws);
    unsigned short* logits = (unsigned short*)(ws);
    unsigned short* A1     = (unsigned short*)(ws + 136 * MiB);
    unsigned short* C1     = A1;
    unsigned short* Cst    = (unsigned short*)(ws + 256 * MiB);
    unsigned short* H2     = (unsigned short*)(ws + 320 * MiB);
    unsigned short* Hraw   = (unsigned short*)(ws + 384 * MiB);
    unsigned short* xbf    = Hraw;
    unsigned short* Wt1b   = (unsigned short*)(ws + 448 * MiB);
    unsigned short* Wt2b   = Wt1b + 512 * 512;
    unsigned short* Wihb   = Wt2b + 512 * 512;
    unsigned short* Whhb   = Wihb + 2048 * 512;
    unsigned short* Wa1b   = Whhb + 2048 * 512;
    unsigned short* Wc1b   = Wa1b + 512 * 512;
    unsigned short* Wa2b   = Wc1b + 512 * 512;
    unsigned short* h_init = Wa2b + 1024 * 512;
    unsigned short* c_init = h_init + 256 * 512;
    unsigned short* zbuf   = c_init + 256 * 512;
    int* rows   = (int*)(zbuf + 512);
    int* counts = rows + 65536;
    int* offs   = counts + S0R;
    int* maxS   = offs + S0R;

    dim3 blk(256);

    // dtype conversions (weights + x), init, segment lists
    cvt8<<<16384, blk, 0, stream>>>(x, xbf);
    cvt8<<<128,  blk, 0, stream>>>(W_t1, Wt1b);
    cvt8<<<128,  blk, 0, stream>>>(W_t2, Wt2b);
    cvt8<<<512,  blk, 0, stream>>>(Wih,  Wihb);
    cvt8<<<512,  blk, 0, stream>>>(Whh,  Whhb);
    cvt8<<<128,  blk, 0, stream>>>(Wa1,  Wa1b);
    cvt8<<<128,  blk, 0, stream>>>(Wc1,  Wc1b);
    wa2pad<<<2048, blk, 0, stream>>>(Wa2, Wa2b);
    init_state<<<256, blk, 0, stream>>>(h0, c0, done, h_init, c_init, zbuf);
    seg_prep<<<1, blk, 0, stream>>>(done, rows, counts, offs, maxS, T);

    // trunk + hoisted x-side gates
    gemm128<true ><<<dim3(4, 512),  blk, 0, stream>>>(xbf, Wt1b, b_t1, nullptr, H1, 512, 512);
    gemm128<true ><<<dim3(4, 512),  blk, 0, stream>>>(H1,  Wt2b, b_t2, nullptr, H2, 512, 512);
    gemm128<false><<<dim3(16, 512), blk, 0, stream>>>(H2,  Wihb, bih,  bhh,    XG, 2048, 2048);

    // segment-parallel LSTM (fused gather-GEMM rounds) + sequential backstop
    static const int Gs[S0R] = {64, 32, 16, 8, 4, 2, 1, 1, 1, 1, 1, 1};
    for (int s = 0; s < S0R; ++s)
        lstm_round<<<dim3(16, Gs[s]), blk, 0, stream>>>(rows, counts, offs, s, XG, Whhb,
                                                        h_init, c_init, zbuf, Hraw, Cst);
    lstm_fixup<<<256, blk, 0, stream>>>(done, maxS, XG, Whhb, Hraw, Cst, T);

    // residual: Hraw <- Hraw + H2 (= new_hidden)
    nh_add<<<16384, blk, 0, stream>>>(Hraw, H2);

    // actor head
    gemm128<true ><<<dim3(4, 512), blk, 0, stream>>>(Hraw, Wa1b, ba1, nullptr, A1, 512, 512);
    gemm128<false><<<dim3(8, 512), blk, 0, stream>>>(A1, Wa2b, ba2, nullptr, logits, 1000, 1024);
    head_reduce<<<TB / 4, blk, 0, stream>>>(logits, action, out, TB);

    // critic head
    gemm128<true ><<<dim3(4, 512), blk, 0, stream>>>(Hraw, Wc1b, bc1, nullptr, C1, 512, 512);
    critic_v<<<TB / 4, blk, 0, stream>>>(C1, Wc2, bc2, out, TB);
}

// Round 4
// 1758.038 us; speedup vs baseline: 10.7594x; 1.3231x over previous
//
#include <hip/hip_runtime.h>
#include <hip/hip_bf16.h>

typedef short v8s __attribute__((ext_vector_type(8)));
typedef float v4f __attribute__((ext_vector_type(4)));

#define S0R 12      // rounds 0..11 via gather-GEMM; lstm_tail covers s >= 12
#define NLEV 244    // tail levels 12..255

__device__ __forceinline__ float bf2f(unsigned short u) {
    union { unsigned int i; float f; } v; v.i = ((unsigned int)u) << 16; return v.f;
}
__device__ __forceinline__ unsigned short f2bf(float f) {
    union { float f; unsigned int i; } v; v.f = f;
    unsigned int x = v.i;
    return (unsigned short)((x + 0x7fffu + ((x >> 16) & 1u)) >> 16);
}
__device__ __forceinline__ float sigmoidf_(float x) { return 1.0f / (1.0f + expf(-x)); }

// async global->LDS, 16B per lane; LDS dst is wave-uniform base + lane*16
__device__ __forceinline__ void gld_lds16(const unsigned short* g, unsigned short* l) {
    __builtin_amdgcn_global_load_lds(
        (const __attribute__((address_space(1))) unsigned int*)g,
        (__attribute__((address_space(3))) unsigned int*)l, 16, 0, 0);
}

// ---------------------------------------------------------------------------
// m97-style GEMM: C[M,Npad] = act(A[M,512] @ W[Npad,512]^T + b1 (+b2)), bf16.
// 128x128 tile, BK=32, global_load_lds staging, XOR-swizzled k-blocks.
// ---------------------------------------------------------------------------
template <bool TANH>
__global__ __launch_bounds__(256)
void gemm128(const unsigned short* __restrict__ Ag, const unsigned short* __restrict__ Wg,
             const float* __restrict__ b1, const float* __restrict__ b2,
             unsigned short* __restrict__ Cg, int Nreal, int Npad)
{
    __shared__ __align__(16) unsigned short As[128 * 32];
    __shared__ __align__(16) unsigned short Bs[128 * 32];
    const int tid  = threadIdx.x;
    const int w    = tid >> 6;
    const int lane = tid & 63;
    const int quad = lane >> 4;
    const int lr   = lane & 15;
    const int wm   = w & 1, wn = w >> 1;
    const int m0   = blockIdx.y * 128;
    const int n0   = blockIdx.x * 128;

    const int srow = lane >> 2;
    const int kblk = (lane & 3) ^ ((lane >> 3) & 3);

    const unsigned short* gA0 = Ag + (size_t)(m0 + w * 16 + srow) * 512 + kblk * 8;
    const unsigned short* gA1 = gA0 + (size_t)64 * 512;
    const unsigned short* gB0 = Wg + (size_t)(n0 + w * 16 + srow) * 512 + kblk * 8;
    const unsigned short* gB1 = gB0 + (size_t)64 * 512;
    unsigned short* lA0 = As + (w * 16) * 32;
    unsigned short* lA1 = As + (64 + w * 16) * 32;
    unsigned short* lB0 = Bs + (w * 16) * 32;
    unsigned short* lB1 = Bs + (64 + w * 16) * 32;

    const int swz = (quad ^ ((lr >> 1) & 3)) * 8;
    int aoff[4], boff[4];
    #pragma unroll
    for (int i = 0; i < 4; ++i) {
        aoff[i] = (wm * 64 + i * 16 + lr) * 32 + swz;
        boff[i] = (wn * 64 + i * 16 + lr) * 32 + swz;
    }

    v4f zz = {0.f, 0.f, 0.f, 0.f};
    v4f acc[4][4] = {{zz,zz,zz,zz},{zz,zz,zz,zz},{zz,zz,zz,zz},{zz,zz,zz,zz}};

    for (int k = 0; k < 16; ++k) {
        __syncthreads();
        gld_lds16(gA0 + k * 32, lA0);
        gld_lds16(gA1 + k * 32, lA1);
        gld_lds16(gB0 + k * 32, lB0);
        gld_lds16(gB1 + k * 32, lB1);
        __syncthreads();
        v8s a[4], b[4];
        #pragma unroll
        for (int i = 0; i < 4; ++i) { a[i] = *(const v8s*)&As[aoff[i]]; b[i] = *(const v8s*)&Bs[boff[i]]; }
        #pragma unroll
        for (int i = 0; i < 4; ++i)
            #pragma unroll
            for (int j = 0; j < 4; ++j)
                acc[i][j] = __builtin_amdgcn_mfma_f32_16x16x32_bf16(a[i], b[j], acc[i][j], 0, 0, 0);
    }

    #pragma unroll
    for (int j = 0; j < 4; ++j) {
        const int nn = n0 + wn * 64 + j * 16 + lr;
        const float bias = (nn < Nreal) ? (b1[nn] + (b2 ? b2[nn] : 0.f)) : 0.f;
        #pragma unroll
        for (int i = 0; i < 4; ++i) {
            #pragma unroll
            for (int r = 0; r < 4; ++r) {
                const int mm = m0 + wm * 64 + i * 16 + quad * 4 + r;
                float v = acc[i][j][r] + bias;
                if (TANH) v = tanhf(v);
                Cg[(size_t)mm * Npad + nn] = f2bf(v);
            }
        }
    }
}

// fp32 -> bf16, 8 elems/thread (n must be multiple of 2048)
__global__ void cvt8(const float* __restrict__ src, unsigned short* __restrict__ dst)
{
    const size_t i = ((size_t)blockIdx.x * 256 + threadIdx.x) * 8;
    float4 f0 = *(const float4*)(src + i);
    float4 f1 = *(const float4*)(src + i + 4);
    unsigned short t8[8];
    t8[0]=f2bf(f0.x); t8[1]=f2bf(f0.y); t8[2]=f2bf(f0.z); t8[3]=f2bf(f0.w);
    t8[4]=f2bf(f1.x); t8[5]=f2bf(f1.y); t8[6]=f2bf(f1.z); t8[7]=f2bf(f1.w);
    *(v8s*)(dst + i) = *(const v8s*)t8;
}

// Wa2 (1000x512 fp32) -> zero-padded 1024x512 bf16
__global__ void wa2pad(const float* __restrict__ src, unsigned short* __restrict__ dst)
{
    const int i = blockIdx.x * 256 + threadIdx.x;
    const int row = i >> 9;
    dst[i] = (row < 1000) ? f2bf(src[(size_t)row * 512 + (i & 511)]) : (unsigned short)0;
}

// masked initial state (bf16) + zero row buffer
__global__ void init_state(const float* __restrict__ h0, const float* __restrict__ c0,
                           const int* __restrict__ done,
                           unsigned short* __restrict__ h_init, unsigned short* __restrict__ c_init,
                           unsigned short* __restrict__ zbuf)
{
    const int b = blockIdx.x;
    const float m = 1.f - (float)done[b];
    for (int k = threadIdx.x; k < 512; k += 256) {
        h_init[(size_t)b * 512 + k] = f2bf(h0[(size_t)b * 512 + k] * m);
        c_init[(size_t)b * 512 + k] = f2bf(c0[(size_t)b * 512 + k] * m);
        if (b == 0) zbuf[k] = 0;
    }
}

// ---------------------------------------------------------------------------
// Segment prep (single WG): one global walk of done (bits cached in LDS),
// per-round row lists for s<12, level-grouped tail list for s>=12,
// maxS, and barrier-counter reset for lstm_tail.
// ---------------------------------------------------------------------------
__global__ __launch_bounds__(256, 1)
void seg_prep(const int* __restrict__ done, int* __restrict__ rows,
              int* __restrict__ counts, int* __restrict__ offs,
              int* __restrict__ trows, int* __restrict__ tcnt, int* __restrict__ toffs,
              int* __restrict__ maxS, int* __restrict__ bar, int T)
{
    __shared__ unsigned int   bits[256][8];
    __shared__ unsigned short cnt[256][S0R];
    __shared__ unsigned short base[256][S0R];
    __shared__ int tot[S0R];
    __shared__ int goff[S0R];
    __shared__ int tcl[NLEV];
    __shared__ int tol[NLEV];
    __shared__ int tpos[NLEV];
    __shared__ int mxl[256];
    const int b = threadIdx.x;
    #pragma unroll
    for (int s = 0; s < S0R; ++s) cnt[b][s] = 0;
    #pragma unroll
    for (int i = 0; i < 8; ++i) bits[b][i] = 0;
    for (int l = b; l < NLEV; l += 256) { tcl[l] = 0; tpos[l] = 0; }
    __syncthreads();

    int s = 0, mx = 0;
    for (int t = 0; t < T; ++t) {
        int d = done[t * 256 + b];
        if (d) bits[b][t >> 5] |= (1u << (t & 31));
        s = (t == 0 || d) ? 0 : s + 1;
        if (s < S0R) cnt[b][s]++;
        else atomicAdd(&tcl[s - S0R], 1);
        mx = mx > s ? mx : s;
    }
    mxl[b] = mx;
    __syncthreads();

    if (b < S0R) {
        int tsum = 0;
        for (int bb = 0; bb < 256; ++bb) { base[bb][b] = (unsigned short)tsum; tsum += cnt[bb][b]; }
        tot[b] = tsum;
    }
    __syncthreads();
    if (b == 0) {
        int run = 0;
        for (int ss = 0; ss < S0R; ++ss) { goff[ss] = run; run += tot[ss]; }
        run = 0;
        for (int l = 0; l < NLEV; ++l) { tol[l] = run; run += tcl[l]; }
        int m = 0;
        for (int bb = 0; bb < 256; ++bb) m = m > mxl[bb] ? m : mxl[bb];
        *maxS = m;
        *bar  = 0;
    }
    __syncthreads();
    if (b < S0R) { counts[b] = tot[b]; offs[b] = goff[b]; }
    for (int l = b; l < NLEV; l += 256) { tcnt[l] = tcl[l]; toffs[l] = tol[l]; }

    s = 0;
    for (int t = 0; t < T; ++t) {
        int d = (bits[b][t >> 5] >> (t & 31)) & 1;
        s = (t == 0 || d) ? 0 : s + 1;
        if (s < S0R) {
            int idx = goff[s] + (int)base[b][s];
            base[b][s]++;
            rows[idx] = t * 256 + b;
        } else {
            int idx = tol[s - S0R] + atomicAdd(&tpos[s - S0R], 1);
            trows[idx] = t * 256 + b;
        }
    }
}

// ---------------------------------------------------------------------------
// Fused LSTM round (s < 12): 128 gathered rows x (4 gates x 32 hidden cols),
// async-staged A/B, LDS gate exchange, fused cell update.
// ---------------------------------------------------------------------------
__global__ __launch_bounds__(256)
void lstm_round(const int* __restrict__ rows, const int* __restrict__ counts,
                const int* __restrict__ offs, int s,
                const unsigned short* __restrict__ XG,
                const unsigned short* __restrict__ Whb,
                const unsigned short* __restrict__ h_init,
                const unsigned short* __restrict__ c_init,
                const unsigned short* __restrict__ zbuf,
                unsigned short* __restrict__ Hraw, unsigned short* __restrict__ Cst)
{
    const int M = counts[s];
    if (M == 0) return;
    const int off    = offs[s];
    const int mtiles = (M + 127) >> 7;

    __shared__ __align__(16) unsigned short As[128 * 32];
    __shared__ __align__(16) unsigned short Bs[128 * 32];
    __shared__ __align__(16) unsigned short Gx[128 * 136];
    __shared__ int rl[128];

    const int tid  = threadIdx.x;
    const int w    = tid >> 6;
    const int lane = tid & 63;
    const int quad = lane >> 4;
    const int lr   = lane & 15;
    const int wm   = w & 1, wn = w >> 1;
    const int c0   = blockIdx.x * 32;
    const int srow = lane >> 2;
    const int kblk = (lane & 3) ^ ((lane >> 3) & 3);

    const int br0 = w * 16 + srow;
    const int br1 = 64 + br0;
    const unsigned short* gB0 = Whb + (size_t)((br0 >> 5) * 512 + c0 + (br0 & 31)) * 512 + kblk * 8;
    const unsigned short* gB1 = Whb + (size_t)((br1 >> 5) * 512 + c0 + (br1 & 31)) * 512 + kblk * 8;
    unsigned short* lA0 = As + (w * 16) * 32;
    unsigned short* lA1 = As + (64 + w * 16) * 32;
    unsigned short* lB0 = Bs + (w * 16) * 32;
    unsigned short* lB1 = Bs + (64 + w * 16) * 32;

    const int swz = (quad ^ ((lr >> 1) & 3)) * 8;
    int aoff[4], boff[4];
    #pragma unroll
    for (int i = 0; i < 4; ++i) {
        aoff[i] = (wm * 64 + i * 16 + lr) * 32 + swz;
        boff[i] = (wn * 64 + i * 16 + lr) * 32 + swz;
    }

    for (int mt = blockIdx.y; mt < mtiles; mt += gridDim.y) {
        __syncthreads();
        if (tid < 128) {
            int li = mt * 128 + tid;
            rl[tid] = (li < M) ? rows[off + li] : -1;
        }
        __syncthreads();

        int g0r = rl[w * 16 + srow];
        int g1r = rl[64 + w * 16 + srow];
        const unsigned short* gA0;
        const unsigned short* gA1;
        if (s == 0) {
            gA0 = (g0r >= 0 && g0r < 256) ? h_init + (size_t)g0r * 512 + kblk * 8 : zbuf + kblk * 8;
            gA1 = (g1r >= 0 && g1r < 256) ? h_init + (size_t)g1r * 512 + kblk * 8 : zbuf + kblk * 8;
        } else {
            gA0 = (g0r >= 0) ? Hraw + (size_t)(g0r - 256) * 512 + kblk * 8 : zbuf + kblk * 8;
            gA1 = (g1r >= 0) ? Hraw + (size_t)(g1r - 256) * 512 + kblk * 8 : zbuf + kblk * 8;
        }

        v4f zz = {0.f, 0.f, 0.f, 0.f};
        v4f acc[4][4] = {{zz,zz,zz,zz},{zz,zz,zz,zz},{zz,zz,zz,zz},{zz,zz,zz,zz}};

        for (int k = 0; k < 16; ++k) {
            __syncthreads();
            gld_lds16(gA0 + k * 32, lA0);
            gld_lds16(gA1 + k * 32, lA1);
            gld_lds16(gB0 + k * 32, lB0);
            gld_lds16(gB1 + k * 32, lB1);
            __syncthreads();
            v8s a[4], b[4];
            #pragma unroll
            for (int i = 0; i < 4; ++i) { a[i] = *(const v8s*)&As[aoff[i]]; b[i] = *(const v8s*)&Bs[boff[i]]; }
            #pragma unroll
            for (int i = 0; i < 4; ++i)
                #pragma unroll
                for (int j = 0; j < 4; ++j)
                    acc[i][j] = __builtin_amdgcn_mfma_f32_16x16x32_bf16(a[i], b[j], acc[i][j], 0, 0, 0);
        }

        #pragma unroll
        for (int j = 0; j < 4; ++j) {
            const int nl = wn * 64 + j * 16 + lr;
            #pragma unroll
            for (int i = 0; i < 4; ++i)
                #pragma unroll
                for (int r = 0; r < 4; ++r)
                    Gx[(wm * 64 + i * 16 + quad * 4 + r) * 136 + nl] = f2bf(acc[i][j][r]);
        }
        __syncthreads();

        {
            const int rloc = tid >> 1;
            const int half = tid & 1;
            const int gr   = rl[rloc];
            if (gr >= 0) {
                #pragma unroll
                for (int ch = 0; ch < 2; ++ch) {
                    const int co = half * 16 + ch * 8;
                    const int kg = c0 + co;
                    v8s q0 = *(const v8s*)&Gx[rloc * 136 +   0 + co];
                    v8s q1 = *(const v8s*)&Gx[rloc * 136 +  32 + co];
                    v8s q2 = *(const v8s*)&Gx[rloc * 136 +  64 + co];
                    v8s q3 = *(const v8s*)&Gx[rloc * 136 +  96 + co];
                    const size_t xb = (size_t)gr * 2048 + kg;
                    v8s x0 = *(const v8s*)&XG[xb];
                    v8s x1 = *(const v8s*)&XG[xb + 512];
                    v8s x2 = *(const v8s*)&XG[xb + 1024];
                    v8s x3 = *(const v8s*)&XG[xb + 1536];
                    float cprev[8];
                    if (s == 0) {
                        if (gr < 256) {
                            v8s cv = *(const v8s*)&c_init[(size_t)gr * 512 + kg];
                            #pragma unroll
                            for (int e = 0; e < 8; ++e) cprev[e] = bf2f((unsigned short)cv[e]);
                        } else {
                            #pragma unroll
                            for (int e = 0; e < 8; ++e) cprev[e] = 0.f;
                        }
                    } else {
                        v8s cv = *(const v8s*)&Cst[(size_t)(gr - 256) * 512 + kg];
                        #pragma unroll
                        for (int e = 0; e < 8; ++e) cprev[e] = bf2f((unsigned short)cv[e]);
                    }
                    unsigned short hc[8], cc[8];
                    #pragma unroll
                    for (int e = 0; e < 8; ++e) {
                        float gi = bf2f((unsigned short)q0[e]) + bf2f((unsigned short)x0[e]);
                        float gf = bf2f((unsigned short)q1[e]) + bf2f((unsigned short)x1[e]);
                        float gg = bf2f((unsigned short)q2[e]) + bf2f((unsigned short)x2[e]);
                        float go = bf2f((unsigned short)q3[e]) + bf2f((unsigned short)x3[e]);
                        float c  = sigmoidf_(gf) * cprev[e] + sigmoidf_(gi) * tanhf(gg);
                        float h  = sigmoidf_(go) * tanhf(c);
                        cc[e] = f2bf(c);
                        hc[e] = f2bf(h);
                    }
                    *(v8s*)&Cst[(size_t)gr * 512 + kg]  = *(const v8s*)cc;
                    *(v8s*)&Hraw[(size_t)gr * 512 + kg] = *(const v8s*)hc;
                }
            }
        }
    }
}

// ---------------------------------------------------------------------------
// Tail (s >= 12): 64 WGs, each holds its 32-row Whh slice (8 hidden cols x
// 4 gates) resident in LDS; levels processed with a device-scope spin barrier
// between them (64 blocks <= 256 CUs, stream-serialized => co-resident;
// monotone arrival counter => no deadlock; seg_prep resets it every call).
// ---------------------------------------------------------------------------
__global__ __launch_bounds__(256, 1)
void lstm_tail(const int* __restrict__ trows, const int* __restrict__ tcnt,
               const int* __restrict__ toffs, const int* __restrict__ maxS_p,
               const unsigned short* __restrict__ XG,
               const unsigned short* __restrict__ Whb,
               unsigned short* __restrict__ Hraw, unsigned short* __restrict__ Cst,
               int* __restrict__ bar)
{
    const int mS = *maxS_p;
    if (mS < S0R) return;
    __shared__ __align__(16) unsigned short Wl[32 * 512];   // 32 KB
    __shared__ __align__(16) unsigned short Hb[16 * 512];   // 16 KB
    __shared__ float Gb[16 * 32];
    __shared__ int rl[16];
    const int j    = blockIdx.x;          // hidden-col slice: cols j*8 .. j*8+8
    const int tid  = threadIdx.x;
    const int w    = tid >> 6;
    const int lane = tid & 63;
    const int quad = lane >> 4;
    const int lr   = lane & 15;

    // resident Whh slice: Wl row n = g*8+c  <-  Whh row g*512 + j*8 + c
    for (int e = tid; e < 32 * 64; e += 256) {
        int n = e >> 6, kb = e & 63;
        int g = n >> 3, c = n & 7;
        *(v8s*)&Wl[n * 512 + kb * 8] = *(const v8s*)&Whb[(size_t)(g * 512 + j * 8 + c) * 512 + kb * 8];
    }

    int target = 0;
    for (int s = S0R; s <= mS; ++s) {
        const int lev = s - S0R;
        const int M   = tcnt[lev];
        const int off = toffs[lev];
        for (int ch = 0; ch < M; ch += 16) {
            __syncthreads();
            if (tid < 16) rl[tid] = (ch + tid < M) ? trows[off + ch + tid] : -1;
            __syncthreads();
            {   // stage h_prev rows (s>=12 => prev always in Hraw)
                int r = tid >> 4, seg = (tid & 15) * 32;
                int gr = rl[r];
                if (gr >= 0) {
                    const unsigned short* src = &Hraw[(size_t)(gr - 256) * 512 + seg];
                    *(v8s*)&Hb[r * 512 + seg]      = *(const v8s*)(src);
                    *(v8s*)&Hb[r * 512 + seg + 8]  = *(const v8s*)(src + 8);
                    *(v8s*)&Hb[r * 512 + seg + 16] = *(const v8s*)(src + 16);
                    *(v8s*)&Hb[r * 512 + seg + 24] = *(const v8s*)(src + 24);
                } else {
                    v8s z = {0,0,0,0,0,0,0,0};
                    *(v8s*)&Hb[r * 512 + seg]      = z;
                    *(v8s*)&Hb[r * 512 + seg + 8]  = z;
                    *(v8s*)&Hb[r * 512 + seg + 16] = z;
                    *(v8s*)&Hb[r * 512 + seg + 24] = z;
                }
            }
            __syncthreads();
            if (w < 2) {      // wave w computes output tile n = w*16 .. w*16+16
                v4f acc = {0.f, 0.f, 0.f, 0.f};
                for (int k = 0; k < 16; ++k) {
                    v8s a = *(const v8s*)&Hb[lr * 512 + k * 32 + quad * 8];
                    v8s b = *(const v8s*)&Wl[(w * 16 + lr) * 512 + k * 32 + quad * 8];
                    acc = __builtin_amdgcn_mfma_f32_16x16x32_bf16(a, b, acc, 0, 0, 0);
                }
                #pragma unroll
                for (int r = 0; r < 4; ++r)
                    Gb[(quad * 4 + r) * 32 + w * 16 + lr] = acc[r];
            }
            __syncthreads();
            if (tid < 128) {
                int r = tid >> 3, c = tid & 7;
                int gr = rl[r];
                if (gr >= 0) {
                    int k = j * 8 + c;
                    const size_t xb = (size_t)gr * 2048 + k;
                    float gi = Gb[r * 32 +  0 + c] + bf2f(XG[xb]);
                    float gf = Gb[r * 32 +  8 + c] + bf2f(XG[xb + 512]);
                    float gg = Gb[r * 32 + 16 + c] + bf2f(XG[xb + 1024]);
                    float go = Gb[r * 32 + 24 + c] + bf2f(XG[xb + 1536]);
                    float cp = bf2f(Cst[(size_t)(gr - 256) * 512 + k]);
                    float cc = sigmoidf_(gf) * cp + sigmoidf_(gi) * tanhf(gg);
                    float hh = sigmoidf_(go) * tanhf(cc);
                    Cst[(size_t)gr * 512 + k]  = f2bf(cc);
                    Hraw[(size_t)gr * 512 + k] = f2bf(hh);
                }
            }
        }
        // inter-level device barrier
        target += 64;
        __threadfence();
        __syncthreads();
        if (tid == 0) {
            __hip_atomic_fetch_add(bar, 1, __ATOMIC_RELEASE, __HIP_MEMORY_SCOPE_AGENT);
            while (__hip_atomic_load(bar, __ATOMIC_ACQUIRE, __HIP_MEMORY_SCOPE_AGENT) < target) {}
        }
        __syncthreads();
        __threadfence();
    }
}

// Hraw += H2 in place (-> new_hidden), 8 elems/thread
__global__ void nh_add(unsigned short* __restrict__ H, const unsigned short* __restrict__ H2)
{
    const size_t i = ((size_t)blockIdx.x * 256 + threadIdx.x) * 8;
    v8s a = *(const v8s*)(H + i);
    v8s b = *(const v8s*)(H2 + i);
    unsigned short t8[8];
    #pragma unroll
    for (int e = 0; e < 8; ++e)
        t8[e] = f2bf(bf2f((unsigned short)a[e]) + bf2f((unsigned short)b[e]));
    *(v8s*)(H + i) = *(const v8s*)t8;
}

// actor head: one wave per row over bf16 logits (stride 1024, 1000 valid)
__global__ void head_reduce(const unsigned short* __restrict__ logits,
                            const int* __restrict__ action,
                            float* __restrict__ out, int TB)
{
    const int r = blockIdx.x * 4 + (threadIdx.x >> 6);
    const int lane = threadIdx.x & 63;
    const unsigned short* row = logits + (size_t)r * 1024;
    float m = -1e30f, Z = 0.f, S = 0.f;
    v8s v0 = *(const v8s*)&row[lane * 8];
    #pragma unroll
    for (int e = 0; e < 8; ++e) {
        float xv = bf2f((unsigned short)v0[e]);
        if (xv > m) { float sc = expf(m - xv); Z *= sc; S *= sc; m = xv; }
        float ev = expf(xv - m);
        Z += ev; S += xv * ev;
    }
    v8s v1 = *(const v8s*)&row[512 + lane * 8];
    #pragma unroll
    for (int e = 0; e < 8; ++e) {
        int c = 512 + lane * 8 + e;
        if (c < 1000) {
            float xv = bf2f((unsigned short)v1[e]);
            if (xv > m) { float sc = expf(m - xv); Z *= sc; S *= sc; m = xv; }
            float ev = expf(xv - m);
            Z += ev; S += xv * ev;
        }
    }
    #pragma unroll
    for (int offb = 32; offb > 0; offb >>= 1) {
        float m2 = __shfl_xor(m, offb);
        float Z2 = __shfl_xor(Z, offb);
        float S2 = __shfl_xor(S, offb);
        float M  = fmaxf(m, m2);
        float s1 = expf(m - M), s2 = expf(m2 - M);
        Z = Z * s1 + Z2 * s2;
        S = S * s1 + S2 * s2;
        m = M;
    }
    if (lane == 0) {
        float lse = m + logf(Z);
        float xa  = bf2f(row[action[r]]);
        out[r]      = xa - lse;
        out[TB + r] = lse - S / Z;
    }
}

__global__ void critic_v(const unsigned short* __restrict__ C1, const float* __restrict__ Wc2,
                         const float* __restrict__ bc2, float* __restrict__ out, int TB)
{
    const int r = blockIdx.x * 4 + (threadIdx.x >> 6);
    const int lane = threadIdx.x & 63;
    const unsigned short* row = C1 + (size_t)r * 512;
    v8s hv = *(const v8s*)&row[lane * 8];
    float4 w0 = *(const float4*)&Wc2[lane * 8];
    float4 w1 = *(const float4*)&Wc2[lane * 8 + 4];
    float s = bf2f((unsigned short)hv[0]) * w0.x + bf2f((unsigned short)hv[1]) * w0.y +
              bf2f((unsigned short)hv[2]) * w0.z + bf2f((unsigned short)hv[3]) * w0.w +
              bf2f((unsigned short)hv[4]) * w1.x + bf2f((unsigned short)hv[5]) * w1.y +
              bf2f((unsigned short)hv[6]) * w1.z + bf2f((unsigned short)hv[7]) * w1.w;
    #pragma unroll
    for (int offb = 32; offb > 0; offb >>= 1) s += __shfl_xor(s, offb);
    if (lane == 0) out[2 * TB + r] = s + bc2[0];
}

extern "C" void kernel_launch(void* const* d_in, const int* in_sizes, int n_in,
                              void* d_out, int out_size, void* d_ws, size_t ws_size,
                              hipStream_t stream)
{
    const float* x    = (const float*)d_in[0];
    const int*  done  = (const int*)d_in[1];
    const int*  action= (const int*)d_in[2];
    const float* W_t1 = (const float*)d_in[4];
    const float* b_t1 = (const float*)d_in[5];
    const float* W_t2 = (const float*)d_in[6];
    const float* b_t2 = (const float*)d_in[7];
    const float* Wih  = (const float*)d_in[8];
    const float* Whh  = (const float*)d_in[9];
    const float* bih  = (const float*)d_in[10];
    const float* bhh  = (const float*)d_in[11];
    const float* Wa1  = (const float*)d_in[12];
    const float* ba1  = (const float*)d_in[13];
    const float* Wa2  = (const float*)d_in[14];
    const float* ba2  = (const float*)d_in[15];
    const float* Wc1  = (const float*)d_in[16];
    const float* bc1  = (const float*)d_in[17];
    const float* Wc2  = (const float*)d_in[18];
    const float* bc2  = (const float*)d_in[19];
    const float* h0   = (const float*)d_in[20];
    const float* c0   = (const float*)d_in[21];
    float* out = (float*)d_out;

    const int TB = in_sizes[1];      // 65536
    const int T  = TB / 256;         // 256

    const size_t MiB = 1024 * 1024;
    char* ws = (char*)d_ws;
    unsigned short* XG     = (unsigned short*)(ws);
    unsigned short* H1     = (unsigned short*)(ws);
    unsigned short* logits = (unsigned short*)(ws);
    unsigned short* A1     = (unsigned short*)(ws + 136 * MiB);
    unsigned short* C1     = A1;
    unsigned short* Cst    = (unsigned short*)(ws + 256 * MiB);
    unsigned short* H2     = (unsigned short*)(ws + 320 * MiB);
    unsigned short* Hraw   = (unsigned short*)(ws + 384 * MiB);
    unsigned short* xbf    = Hraw;
    unsigned short* Wt1b   = (unsigned short*)(ws + 448 * MiB);
    unsigned short* Wt2b   = Wt1b + 512 * 512;
    unsigned short* Wihb   = Wt2b + 512 * 512;
    unsigned short* Whhb   = Wihb + 2048 * 512;
    unsigned short* Wa1b   = Whhb + 2048 * 512;
    unsigned short* Wc1b   = Wa1b + 512 * 512;
    unsigned short* Wa2b   = Wc1b + 512 * 512;
    unsigned short* h_init = Wa2b + 1024 * 512;
    unsigned short* c_init = h_init + 256 * 512;
    unsigned short* zbuf   = c_init + 256 * 512;
    int* rows   = (int*)(zbuf + 512);
    int* trows  = rows + 65536;
    int* counts = trows + 65536;
    int* offs   = counts + S0R;
    int* tcnt   = offs + S0R;
    int* toffs  = tcnt + NLEV;
    int* maxS   = toffs + NLEV;
    int* bar    = maxS + 1;

    dim3 blk(256);

    // dtype conversions (weights + x), init, segment lists
    cvt8<<<16384, blk, 0, stream>>>(x, xbf);
    cvt8<<<128,  blk, 0, stream>>>(W_t1, Wt1b);
    cvt8<<<128,  blk, 0, stream>>>(W_t2, Wt2b);
    cvt8<<<512,  blk, 0, stream>>>(Wih,  Wihb);
    cvt8<<<512,  blk, 0, stream>>>(Whh,  Whhb);
    cvt8<<<128,  blk, 0, stream>>>(Wa1,  Wa1b);
    cvt8<<<128,  blk, 0, stream>>>(Wc1,  Wc1b);
    wa2pad<<<2048, blk, 0, stream>>>(Wa2, Wa2b);
    init_state<<<256, blk, 0, stream>>>(h0, c0, done, h_init, c_init, zbuf);
    seg_prep<<<1, blk, 0, stream>>>(done, rows, counts, offs, trows, tcnt, toffs, maxS, bar, T);

    // trunk + hoisted x-side gates
    gemm128<true ><<<dim3(4, 512),  blk, 0, stream>>>(xbf, Wt1b, b_t1, nullptr, H1, 512, 512);
    gemm128<true ><<<dim3(4, 512),  blk, 0, stream>>>(H1,  Wt2b, b_t2, nullptr, H2, 512, 512);
    gemm128<false><<<dim3(16, 512), blk, 0, stream>>>(H2,  Wihb, bih,  bhh,    XG, 2048, 2048);

    // segment-parallel LSTM: 12 gather-GEMM rounds + resident-weight tail
    static const int Gs[S0R] = {256, 128, 64, 32, 16, 8, 4, 2, 1, 1, 1, 1};
    for (int s = 0; s < S0R; ++s)
        lstm_round<<<dim3(16, Gs[s]), blk, 0, stream>>>(rows, counts, offs, s, XG, Whhb,
                                                        h_init, c_init, zbuf, Hraw, Cst);
    lstm_tail<<<64, blk, 0, stream>>>(trows, tcnt, toffs, maxS, XG, Whhb, Hraw, Cst, bar);

    // residual: Hraw <- Hraw + H2 (= new_hidden)
    nh_add<<<16384, blk, 0, stream>>>(Hraw, H2);

    // actor head
    gemm128<true ><<<dim3(4, 512), blk, 0, stream>>>(Hraw, Wa1b, ba1, nullptr, A1, 512, 512);
    gemm128<false><<<dim3(8, 512), blk, 0, stream>>>(A1, Wa2b, ba2, nullptr, logits, 1000, 1024);
    head_reduce<<<TB / 4, blk, 0, stream>>>(logits, action, out, TB);

    // critic head
    gemm128<true ><<<dim3(4, 512), blk, 0, stream>>>(Hraw, Wc1b, bc1, nullptr, C1, 512, 512);
    critic_v<<<TB / 4, blk, 0, stream>>>(C1, Wc2, bc2, out, TB);
}